// Round 1
// baseline (795.867 us; speedup 1.0000x reference)
//
#include <hip/hip_runtime.h>

// NonLocal block: B=4, C=256, P=128, H=W=64, N=4096.
// Pipeline: proj(QKV) -> flash-attn (no-max-sub softmax, valid since |logit|<~2) ->
//           z=Wz*y + BN-stats -> BN finalize -> elementwise out.
// fp32 accumulate everywhere; K/V stored bf16 (error analysis: eps-amplified BN needs
// |err_z| < 3e-4; bf16 K/V contributes ~1e-5).

#define SCALE_ 0.08838834764831845f  // 1/sqrt(128)

__device__ inline unsigned short f2bf(float f) {  // RNE float->bf16
  unsigned int u = __float_as_uint(f);
  u += 0x7fffu + ((u >> 16) & 1u);
  return (unsigned short)(u >> 16);
}
__device__ inline float bflo(unsigned int u) { return __uint_as_float(u << 16); }
__device__ inline float bfhi(unsigned int u) { return __uint_as_float(u & 0xffff0000u); }

// ---------------- 1) projections: Q/K/V[b][n][p] = W[p][c] * x[b][c][n] + bias ----------------
__global__ __launch_bounds__(256) void proj_kernel(
    const float* __restrict__ x,
    const float* __restrict__ Wt, const float* __restrict__ bt,
    const float* __restrict__ Wp, const float* __restrict__ bp,
    const float* __restrict__ Wg, const float* __restrict__ bg,
    float* __restrict__ Qp, unsigned short* __restrict__ Kb, unsigned short* __restrict__ Vb) {
  __shared__ float sW[128 * 64];  // [p][c4 ^ ((p>>2)&7)] float4-col swizzle
  __shared__ float sX[64 * 64];   // [c][n] plain
  const int tid = threadIdx.x;
  const int n0 = blockIdx.x * 64;
  const int sel = blockIdx.y;  // 0=t->Q, 1=p->K, 2=g->V
  const int b = blockIdx.z;
  const float* W = sel == 0 ? Wt : (sel == 1 ? Wp : Wg);
  const float* bias = sel == 0 ? bt : (sel == 1 ? bp : bg);
  const int pg = tid & 31, ng = tid >> 5;  // thread tile: 4p x 8n
  const int nb = ng * 8;
  float acc[4][8];
#pragma unroll
  for (int i = 0; i < 4; ++i)
#pragma unroll
    for (int n = 0; n < 8; ++n) acc[i][n] = 0.f;

  for (int c0 = 0; c0 < 256; c0 += 64) {
    __syncthreads();
#pragma unroll
    for (int it = 0; it < 8; ++it) {
      int e4 = it * 256 + tid;
      int p = e4 >> 4, cQ = e4 & 15;
      float4 v = *(const float4*)(W + p * 256 + c0 + cQ * 4);
      *(float4*)(sW + p * 64 + ((cQ ^ ((p >> 2) & 7)) << 2)) = v;
    }
#pragma unroll
    for (int it = 0; it < 4; ++it) {
      int e4 = it * 256 + tid;
      int cc = e4 >> 4, nn4 = e4 & 15;
      float4 v = *(const float4*)(x + (size_t)(b * 256 + c0 + cc) * 4096 + n0 + nn4 * 4);
      *(float4*)(sX + cc * 64 + nn4 * 4) = v;
    }
    __syncthreads();
    const int sw = pg & 7;
#pragma unroll 2
    for (int c4 = 0; c4 < 16; ++c4) {
      int wo = ((c4 ^ sw) << 2);
      const float* wbse = sW + pg * 256 + wo;  // rows pg*4.. stride 64
      float4 w0 = *(const float4*)(wbse);
      float4 w1 = *(const float4*)(wbse + 64);
      float4 w2 = *(const float4*)(wbse + 128);
      float4 w3 = *(const float4*)(wbse + 192);
#define PROJ_CC(CMP, XROW)                                                               \
  {                                                                                      \
    const float* xr = sX + (XROW) * 64 + nb;                                             \
    float4 xa = *(const float4*)(xr);                                                    \
    float4 xb = *(const float4*)(xr + 4);                                                \
    acc[0][0] += w0.CMP * xa.x; acc[0][1] += w0.CMP * xa.y;                              \
    acc[0][2] += w0.CMP * xa.z; acc[0][3] += w0.CMP * xa.w;                              \
    acc[0][4] += w0.CMP * xb.x; acc[0][5] += w0.CMP * xb.y;                              \
    acc[0][6] += w0.CMP * xb.z; acc[0][7] += w0.CMP * xb.w;                              \
    acc[1][0] += w1.CMP * xa.x; acc[1][1] += w1.CMP * xa.y;                              \
    acc[1][2] += w1.CMP * xa.z; acc[1][3] += w1.CMP * xa.w;                              \
    acc[1][4] += w1.CMP * xb.x; acc[1][5] += w1.CMP * xb.y;                              \
    acc[1][6] += w1.CMP * xb.z; acc[1][7] += w1.CMP * xb.w;                              \
    acc[2][0] += w2.CMP * xa.x; acc[2][1] += w2.CMP * xa.y;                              \
    acc[2][2] += w2.CMP * xa.z; acc[2][3] += w2.CMP * xa.w;                              \
    acc[2][4] += w2.CMP * xb.x; acc[2][5] += w2.CMP * xb.y;                              \
    acc[2][6] += w2.CMP * xb.z; acc[2][7] += w2.CMP * xb.w;                              \
    acc[3][0] += w3.CMP * xa.x; acc[3][1] += w3.CMP * xa.y;                              \
    acc[3][2] += w3.CMP * xa.z; acc[3][3] += w3.CMP * xa.w;                              \
    acc[3][4] += w3.CMP * xb.x; acc[3][5] += w3.CMP * xb.y;                              \
    acc[3][6] += w3.CMP * xb.z; acc[3][7] += w3.CMP * xb.w;                              \
  }
      PROJ_CC(x, c4 * 4 + 0)
      PROJ_CC(y, c4 * 4 + 1)
      PROJ_CC(z, c4 * 4 + 2)
      PROJ_CC(w, c4 * 4 + 3)
    }
  }
  float4 bv = *(const float4*)(bias + pg * 4);
#pragma unroll
  for (int n = 0; n < 8; ++n) {
    float v0 = acc[0][n] + bv.x;
    float v1 = acc[1][n] + bv.y;
    float v2 = acc[2][n] + bv.z;
    float v3 = acc[3][n] + bv.w;
    size_t off = (size_t)(b * 4096 + n0 + nb + n) * 128 + pg * 4;
    if (sel == 0) {
      *(float4*)(Qp + off) = make_float4(v0, v1, v2, v3);
    } else {
      ushort4 us;
      us.x = f2bf(v0); us.y = f2bf(v1); us.z = f2bf(v2); us.w = f2bf(v3);
      *(ushort4*)((sel == 1 ? Kb : Vb) + off) = us;
    }
  }
}

// ---------------- 2) attention: y[b][n][p] = softmax(Q K^T) V ----------------
// 64 query rows/block, 512 threads. Per-thread: 2 rows x 4 keys (QK), 2 rows x 8 dims (PV).
// LDS (dynamic, 112 KiB): sQ[64][128] (fp32, pre-scaled), sK/sV[64][128] (fp32 from bf16),
// sP[64][64]. All tiles XOR-swizzled on float4 columns by their row-group to kill conflicts.
__global__ __launch_bounds__(512, 2) void attn_kernel(
    const float* __restrict__ Qp, const unsigned short* __restrict__ Kb,
    const unsigned short* __restrict__ Vb, float* __restrict__ Yp) {
  extern __shared__ float smem[];
  float* sQ = smem;           // 8192 floats
  float* sK = smem + 8192;    // 8192
  float* sV = smem + 16384;   // 8192
  float* sP = smem + 24576;   // 4096
  const int tid = threadIdx.x;
  const int b = blockIdx.y;
  const int n0 = blockIdx.x * 64;
  const int rg = tid >> 4;   // 0..31 row-group (2 rows)
  const int kg = tid & 15;   // QK key-group (4 keys); PV dim-group
  const int dg = kg;
  const int r0 = rg * 2, r1 = r0 + 1;
  const int sqq = rg & 7;  // swizzle key for Q and P rows (r>>1)&7
  const int skk = kg & 7;  // swizzle key for this thread's K rows (k>>2)&7

  // stage Q (fold 1/sqrt(P) here)
#pragma unroll
  for (int it = 0; it < 4; ++it) {
    int e4 = it * 512 + tid;
    int r = e4 >> 5, c4 = e4 & 31;
    float4 v = *(const float4*)(Qp + (size_t)(b * 4096 + n0 + r) * 128 + c4 * 4);
    v.x *= SCALE_; v.y *= SCALE_; v.z *= SCALE_; v.w *= SCALE_;
    *(float4*)(sQ + r * 128 + ((c4 ^ ((r >> 1) & 7)) << 2)) = v;
  }

  float den0 = 0.f, den1 = 0.f;
  float o00x = 0, o00y = 0, o00z = 0, o00w = 0, o01x = 0, o01y = 0, o01z = 0, o01w = 0;
  float o10x = 0, o10y = 0, o10z = 0, o10w = 0, o11x = 0, o11y = 0, o11z = 0, o11w = 0;
  const float* qb0 = sQ + r0 * 128;
  const float* qb1 = sQ + r1 * 128;
  const float* kb = sK + kg * 512;

  for (int t = 0; t < 64; ++t) {
    const int k0 = t * 64;
    __syncthreads();  // prev PV done; safe to overwrite K/V
    // stage K,V tile (bf16 global -> fp32 LDS, swizzled)
#pragma unroll
    for (int it = 0; it < 2; ++it) {
      int e8 = it * 512 + tid;
      int k = e8 >> 4, m8 = e8 & 15;
      int sk = (k >> 2) & 7;
      int ca = ((m8 * 2) ^ sk) << 2;
      int cb = ((m8 * 2 + 1) ^ sk) << 2;
      size_t gidx = (size_t)(b * 4096 + k0 + k) * 128 + m8 * 8;
      uint4 kv = *(const uint4*)(Kb + gidx);
      uint4 vv = *(const uint4*)(Vb + gidx);
      *(float4*)(sK + k * 128 + ca) = make_float4(bflo(kv.x), bfhi(kv.x), bflo(kv.y), bfhi(kv.y));
      *(float4*)(sK + k * 128 + cb) = make_float4(bflo(kv.z), bfhi(kv.z), bflo(kv.w), bfhi(kv.w));
      *(float4*)(sV + k * 128 + ca) = make_float4(bflo(vv.x), bfhi(vv.x), bflo(vv.y), bfhi(vv.y));
      *(float4*)(sV + k * 128 + cb) = make_float4(bflo(vv.z), bfhi(vv.z), bflo(vv.w), bfhi(vv.w));
    }
    __syncthreads();
    // QK^T: 2 rows x 4 keys per thread
    float a00 = 0, a01 = 0, a02 = 0, a03 = 0, a10 = 0, a11 = 0, a12 = 0, a13 = 0;
#pragma unroll 4
    for (int u = 0; u < 32; ++u) {
      int qo = (u ^ sqq) << 2;
      int ko = (u ^ skk) << 2;
      float4 q0 = *(const float4*)(qb0 + qo);
      float4 q1 = *(const float4*)(qb1 + qo);
      float4 k0v = *(const float4*)(kb + ko);
      float4 k1v = *(const float4*)(kb + 128 + ko);
      float4 k2v = *(const float4*)(kb + 256 + ko);
      float4 k3v = *(const float4*)(kb + 384 + ko);
#define D4(A, Q, K) A += Q.x * K.x; A += Q.y * K.y; A += Q.z * K.z; A += Q.w * K.w;
      D4(a00, q0, k0v) D4(a01, q0, k1v) D4(a02, q0, k2v) D4(a03, q0, k3v)
      D4(a10, q1, k0v) D4(a11, q1, k1v) D4(a12, q1, k2v) D4(a13, q1, k3v)
    }
    // exp (logits tiny: no max-subtraction needed), row-denominator via 16-lane reduce
    float e00 = __expf(a00), e01 = __expf(a01), e02 = __expf(a02), e03 = __expf(a03);
    float e10 = __expf(a10), e11 = __expf(a11), e12 = __expf(a12), e13 = __expf(a13);
    float s0 = (e00 + e01) + (e02 + e03);
    float s1 = (e10 + e11) + (e12 + e13);
#pragma unroll
    for (int m = 1; m < 16; m <<= 1) {
      s0 += __shfl_xor(s0, m);
      s1 += __shfl_xor(s1, m);
    }
    den0 += s0;
    den1 += s1;
    int po = (kg ^ sqq) << 2;
    *(float4*)(sP + r0 * 64 + po) = make_float4(e00, e01, e02, e03);
    *(float4*)(sP + r1 * 64 + po) = make_float4(e10, e11, e12, e13);
    __syncthreads();
    // PV: 2 rows x 8 dims (dims dg*4..+3 and 64+dg*4..+3)
#pragma unroll 2
    for (int kc = 0; kc < 16; ++kc) {
      int pco = (kc ^ sqq) << 2;
      float4 pav = *(const float4*)(sP + r0 * 64 + pco);
      float4 pbv = *(const float4*)(sP + r1 * 64 + pco);
      int off = ((dg ^ (kc & 7)) << 2);
      const float* vrow = sV + kc * 512 + off;
#define PVS(PJ, QJ, RO)                                                       \
  {                                                                           \
    float4 va = *(const float4*)(vrow + RO);                                  \
    float4 vc = *(const float4*)(vrow + RO + 64);                             \
    o00x += PJ * va.x; o00y += PJ * va.y; o00z += PJ * va.z; o00w += PJ * va.w; \
    o01x += PJ * vc.x; o01y += PJ * vc.y; o01z += PJ * vc.z; o01w += PJ * vc.w; \
    o10x += QJ * va.x; o10y += QJ * va.y; o10z += QJ * va.z; o10w += QJ * va.w; \
    o11x += QJ * vc.x; o11y += QJ * vc.y; o11z += QJ * vc.z; o11w += QJ * vc.w; \
  }
      PVS(pav.x, pbv.x, 0)
      PVS(pav.y, pbv.y, 128)
      PVS(pav.z, pbv.z, 256)
      PVS(pav.w, pbv.w, 384)
    }
  }
  const float i0 = 1.0f / den0, i1 = 1.0f / den1;
  size_t yb0 = (size_t)(b * 4096 + n0 + r0) * 128;
  size_t yb1 = (size_t)(b * 4096 + n0 + r1) * 128;
  *(float4*)(Yp + yb0 + dg * 4) = make_float4(o00x * i0, o00y * i0, o00z * i0, o00w * i0);
  *(float4*)(Yp + yb0 + 64 + dg * 4) = make_float4(o01x * i0, o01y * i0, o01z * i0, o01w * i0);
  *(float4*)(Yp + yb1 + dg * 4) = make_float4(o10x * i1, o10y * i1, o10z * i1, o10w * i1);
  *(float4*)(Yp + yb1 + 64 + dg * 4) = make_float4(o11x * i1, o11y * i1, o11z * i1, o11w * i1);
}

// ---------------- 3) z = Wz*y + bz, with fused BN partial stats ----------------
__global__ __launch_bounds__(256) void zbn_kernel(
    const float* __restrict__ Yp, const float* __restrict__ Wz, const float* __restrict__ bz,
    float* __restrict__ Z, float* __restrict__ S1, float* __restrict__ S2) {
  __shared__ float sY[64 * 128];  // [n][p4 ^ ((n>>2)&7)]
  __shared__ float sW[64 * 128];  // [c][p4 ^ ((c>>2)&7)]
  const int tid = threadIdx.x;
  const int b = blockIdx.y;
  const int n0 = blockIdx.x * 64;
  const int cg = tid >> 4, ng = tid & 15;  // 4c x 4n per thread
  const int swc = cg & 7, syn = ng & 7;
#pragma unroll
  for (int it = 0; it < 8; ++it) {
    int e4 = it * 256 + tid;
    int n = e4 >> 5, p4 = e4 & 31;
    float4 v = *(const float4*)(Yp + (size_t)(b * 4096 + n0 + n) * 128 + p4 * 4);
    *(float4*)(sY + n * 128 + ((p4 ^ ((n >> 2) & 7)) << 2)) = v;
  }
  for (int c0 = 0; c0 < 256; c0 += 64) {
    __syncthreads();
#pragma unroll
    for (int it = 0; it < 8; ++it) {
      int e4 = it * 256 + tid;
      int c = e4 >> 5, p4 = e4 & 31;
      float4 v = *(const float4*)(Wz + (size_t)(c0 + c) * 128 + p4 * 4);
      *(float4*)(sW + c * 128 + ((p4 ^ ((c >> 2) & 7)) << 2)) = v;
    }
    __syncthreads();
    float acc[4][4];
#pragma unroll
    for (int i = 0; i < 4; ++i)
#pragma unroll
      for (int j = 0; j < 4; ++j) acc[i][j] = 0.f;
    const float* wb = sW + cg * 512;
    const float* yb = sY + ng * 512;
#pragma unroll 4
    for (int u = 0; u < 32; ++u) {
      int wo = (u ^ swc) << 2;
      int yo = (u ^ syn) << 2;
      float4 w0 = *(const float4*)(wb + wo);
      float4 w1 = *(const float4*)(wb + 128 + wo);
      float4 w2 = *(const float4*)(wb + 256 + wo);
      float4 w3 = *(const float4*)(wb + 384 + wo);
      float4 y0 = *(const float4*)(yb + yo);
      float4 y1 = *(const float4*)(yb + 128 + yo);
      float4 y2 = *(const float4*)(yb + 256 + yo);
      float4 y3 = *(const float4*)(yb + 384 + yo);
      D4(acc[0][0], w0, y0) D4(acc[0][1], w0, y1) D4(acc[0][2], w0, y2) D4(acc[0][3], w0, y3)
      D4(acc[1][0], w1, y0) D4(acc[1][1], w1, y1) D4(acc[1][2], w1, y2) D4(acc[1][3], w1, y3)
      D4(acc[2][0], w2, y0) D4(acc[2][1], w2, y1) D4(acc[2][2], w2, y2) D4(acc[2][3], w2, y3)
      D4(acc[3][0], w3, y0) D4(acc[3][1], w3, y1) D4(acc[3][2], w3, y2) D4(acc[3][3], w3, y3)
    }
#pragma unroll
    for (int i = 0; i < 4; ++i) {
      int c = c0 + cg * 4 + i;
      float bzv = bz[c];
      float z0 = acc[i][0] + bzv, z1 = acc[i][1] + bzv, z2 = acc[i][2] + bzv, z3 = acc[i][3] + bzv;
      *(float4*)(Z + (size_t)(b * 256 + c) * 4096 + n0 + ng * 4) = make_float4(z0, z1, z2, z3);
      float s1 = (z0 + z1) + (z2 + z3);
      float s2 = (z0 * z0 + z1 * z1) + (z2 * z2 + z3 * z3);
#pragma unroll
      for (int m = 1; m < 16; m <<= 1) {
        s1 += __shfl_xor(s1, m);
        s2 += __shfl_xor(s2, m);
      }
      if (ng == 0) {
        atomicAdd(&S1[c], s1);
        atomicAdd(&S2[c], s2);
      }
    }
  }
}

// ---------------- 4) BN finalize: per-channel scale/shift ----------------
__global__ void bnfin_kernel(const float* __restrict__ S1, const float* __restrict__ S2,
                             const float* __restrict__ gamma, const float* __restrict__ beta,
                             float* __restrict__ Scale, float* __restrict__ Shift) {
  int c = threadIdx.x;
  const float inv_cnt = 1.0f / 16384.0f;  // B*N
  float mean = S1[c] * inv_cnt;
  float var = S2[c] * inv_cnt - mean * mean;
  var = fmaxf(var, 0.0f);
  float inv = rsqrtf(var + 1e-5f);
  float sc = gamma[c] * inv;
  Scale[c] = sc;
  Shift[c] = beta[c] - mean * sc;
}

// ---------------- 5) out = z*scale + shift + x ----------------
__global__ __launch_bounds__(256) void out_kernel(
    const float* __restrict__ Z, const float* __restrict__ x,
    const float* __restrict__ Scale, const float* __restrict__ Shift,
    float* __restrict__ out) {
  int i4 = blockIdx.x * 256 + threadIdx.x;
  int flat = i4 << 2;
  int c = (flat >> 12) & 255;
  float4 z = *(const float4*)(Z + flat);
  float4 xv = *(const float4*)(x + flat);
  float sc = Scale[c], sh = Shift[c];
  float4 o;
  o.x = z.x * sc + sh + xv.x;
  o.y = z.y * sc + sh + xv.y;
  o.z = z.z * sc + sh + xv.z;
  o.w = z.w * sc + sh + xv.w;
  *(float4*)(out + flat) = o;
}

extern "C" void kernel_launch(void* const* d_in, const int* in_sizes, int n_in,
                              void* d_out, int out_size, void* d_ws, size_t ws_size,
                              hipStream_t stream) {
  (void)in_sizes; (void)n_in; (void)out_size; (void)ws_size;
  const float* x = (const float*)d_in[0];
  const float* Wt = (const float*)d_in[1];
  const float* bt = (const float*)d_in[2];
  const float* Wp = (const float*)d_in[3];
  const float* bp = (const float*)d_in[4];
  const float* Wg = (const float*)d_in[5];
  const float* bg = (const float*)d_in[6];
  const float* Wz = (const float*)d_in[7];
  const float* bz = (const float*)d_in[8];
  const float* gamma = (const float*)d_in[9];
  const float* beta = (const float*)d_in[10];

  float* ws = (float*)d_ws;
  float* Q = ws;                                              // 2,097,152 f32
  unsigned short* Kb = (unsigned short*)(ws + 2097152);       // 2,097,152 bf16
  unsigned short* Vb = Kb + 2097152;                          // 2,097,152 bf16
  float* Y = (float*)(Vb + 2097152);                          // 2,097,152 f32
  float* Z = Y + 2097152;                                     // 4,194,304 f32
  float* S1 = Z + 4194304;                                    // 256
  float* S2 = S1 + 256;                                       // 256
  float* Scale = S2 + 256;                                    // 256
  float* Shift = Scale + 256;                                 // 256

  hipMemsetAsync(S1, 0, 512 * sizeof(float), stream);

  proj_kernel<<<dim3(64, 3, 4), 256, 0, stream>>>(x, Wt, bt, Wp, bp, Wg, bg, Q, Kb, Vb);

  static const int attn_lds = 28672 * sizeof(float);  // 112 KiB
  hipFuncSetAttribute((const void*)attn_kernel,
                      hipFuncAttributeMaxDynamicSharedMemorySize, attn_lds);
  attn_kernel<<<dim3(64, 4), 512, attn_lds, stream>>>(Q, Kb, Vb, Y);

  zbn_kernel<<<dim3(64, 4), 256, 0, stream>>>(Y, Wz, bz, Z, S1, S2);
  bnfin_kernel<<<1, 256, 0, stream>>>(S1, S2, gamma, beta, Scale, Shift);
  out_kernel<<<4096, 256, 0, stream>>>(Z, x, Scale, Shift, (float*)d_out);
}

// Round 4
// 291.159 us; speedup vs baseline: 2.7334x; 2.7334x over previous
//
#include <hip/hip_runtime.h>

// NonLocal block: B=4, C=256, P=128, H=W=64, N=4096.
// proj(Q,K bf16 [b][n][p]; V^T bf16 [b][p][n]) -> MFMA flash-attn (no-max softmax,
// S^T=mfma(K,Q), Y^T=mfma(V^T,P^T), kv-split=2) -> zbn (combine+normalize Y, z=Wz*y,
// fused BN stats) -> BN finalize -> elementwise out.
// R3 fix: zbn sW staging covered only p<64 of [64][128] (4 iters, c>>4/c&15) ->
// GEMM read uninitialized LDS. Now 8 iters, cc=c>>5, p4=c&31.

#define SCALE_ 0.08838834764831845f  // 1/sqrt(128)

typedef __bf16 bf16x8 __attribute__((ext_vector_type(8)));
typedef float f32x4 __attribute__((ext_vector_type(4)));
typedef unsigned short ushort8v __attribute__((ext_vector_type(8)));

__device__ inline unsigned short f2bf(float f) {  // RNE float->bf16
  unsigned int u = __float_as_uint(f);
  u += 0x7fffu + ((u >> 16) & 1u);
  return (unsigned short)(u >> 16);
}

// ---------------- 1) projections ----------------
// Q[b][n][p] = (Wt x + bt) * SCALE_  (bf16)
// K[b][n][p] = Wp x + bp             (bf16)
// Vt[b][p][n] = Wg x + bg            (bf16, transposed)
__global__ __launch_bounds__(256) void proj_kernel(
    const float* __restrict__ x,
    const float* __restrict__ Wt, const float* __restrict__ bt,
    const float* __restrict__ Wp, const float* __restrict__ bp,
    const float* __restrict__ Wg, const float* __restrict__ bg,
    unsigned short* __restrict__ Qb, unsigned short* __restrict__ Kb,
    unsigned short* __restrict__ Vtb) {
  __shared__ float sW[128 * 64];  // [p][c4 ^ ((p>>2)&7)] float4-col swizzle
  __shared__ float sX[64 * 64];   // [c][n]
  const int tid = threadIdx.x;
  const int n0 = blockIdx.x * 64;
  const int sel = blockIdx.y;  // 0=t->Q, 1=p->K, 2=g->Vt
  const int b = blockIdx.z;
  const float* W = sel == 0 ? Wt : (sel == 1 ? Wp : Wg);
  const float* bias = sel == 0 ? bt : (sel == 1 ? bp : bg);
  const int pg = tid & 31, ng = tid >> 5;  // thread tile: 4p x 8n
  const int nb = ng * 8;
  float acc[4][8];
#pragma unroll
  for (int i = 0; i < 4; ++i)
#pragma unroll
    for (int n = 0; n < 8; ++n) acc[i][n] = 0.f;

  for (int c0 = 0; c0 < 256; c0 += 64) {
    __syncthreads();
#pragma unroll
    for (int it = 0; it < 8; ++it) {
      int e4 = it * 256 + tid;
      int p = e4 >> 4, cQ = e4 & 15;
      float4 v = *(const float4*)(W + p * 256 + c0 + cQ * 4);
      *(float4*)(sW + p * 64 + ((cQ ^ ((p >> 2) & 7)) << 2)) = v;
    }
#pragma unroll
    for (int it = 0; it < 4; ++it) {
      int e4 = it * 256 + tid;
      int cc = e4 >> 4, nn4 = e4 & 15;
      float4 v = *(const float4*)(x + (size_t)(b * 256 + c0 + cc) * 4096 + n0 + nn4 * 4);
      *(float4*)(sX + cc * 64 + nn4 * 4) = v;
    }
    __syncthreads();
    const int sw = pg & 7;
#pragma unroll 2
    for (int c4 = 0; c4 < 16; ++c4) {
      int wo = ((c4 ^ sw) << 2);
      const float* wbse = sW + pg * 256 + wo;
      float4 w0 = *(const float4*)(wbse);
      float4 w1 = *(const float4*)(wbse + 64);
      float4 w2 = *(const float4*)(wbse + 128);
      float4 w3 = *(const float4*)(wbse + 192);
#define PROJ_CC(CMP, XROW)                                                               \
  {                                                                                      \
    const float* xr = sX + (XROW) * 64 + nb;                                             \
    float4 xa = *(const float4*)(xr);                                                    \
    float4 xb = *(const float4*)(xr + 4);                                                \
    acc[0][0] += w0.CMP * xa.x; acc[0][1] += w0.CMP * xa.y;                              \
    acc[0][2] += w0.CMP * xa.z; acc[0][3] += w0.CMP * xa.w;                              \
    acc[0][4] += w0.CMP * xb.x; acc[0][5] += w0.CMP * xb.y;                              \
    acc[0][6] += w0.CMP * xb.z; acc[0][7] += w0.CMP * xb.w;                              \
    acc[1][0] += w1.CMP * xa.x; acc[1][1] += w1.CMP * xa.y;                              \
    acc[1][2] += w1.CMP * xa.z; acc[1][3] += w1.CMP * xa.w;                              \
    acc[1][4] += w1.CMP * xb.x; acc[1][5] += w1.CMP * xb.y;                              \
    acc[1][6] += w1.CMP * xb.z; acc[1][7] += w1.CMP * xb.w;                              \
    acc[2][0] += w2.CMP * xa.x; acc[2][1] += w2.CMP * xa.y;                              \
    acc[2][2] += w2.CMP * xa.z; acc[2][3] += w2.CMP * xa.w;                              \
    acc[2][4] += w2.CMP * xb.x; acc[2][5] += w2.CMP * xb.y;                              \
    acc[2][6] += w2.CMP * xb.z; acc[2][7] += w2.CMP * xb.w;                              \
    acc[3][0] += w3.CMP * xa.x; acc[3][1] += w3.CMP * xa.y;                              \
    acc[3][2] += w3.CMP * xa.z; acc[3][3] += w3.CMP * xa.w;                              \
    acc[3][4] += w3.CMP * xb.x; acc[3][5] += w3.CMP * xb.y;                              \
    acc[3][6] += w3.CMP * xb.z; acc[3][7] += w3.CMP * xb.w;                              \
  }
      PROJ_CC(x, c4 * 4 + 0)
      PROJ_CC(y, c4 * 4 + 1)
      PROJ_CC(z, c4 * 4 + 2)
      PROJ_CC(w, c4 * 4 + 3)
    }
  }
  float4 bv = *(const float4*)(bias + pg * 4);
  const float* bvf = (const float*)&bv;
  if (sel == 2) {
    // V: transposed write [b][p][n], 8 contiguous n per p-row
#pragma unroll
    for (int i = 0; i < 4; ++i) {
      ushort8v us;
#pragma unroll
      for (int n = 0; n < 8; ++n) us[n] = f2bf(acc[i][n] + bvf[i]);
      *(ushort8v*)(Vtb + (size_t)(b * 128 + pg * 4 + i) * 4096 + n0 + nb) = us;
    }
  } else {
    const float sc = sel == 0 ? SCALE_ : 1.0f;
    unsigned short* dst = sel == 0 ? Qb : Kb;
#pragma unroll
    for (int n = 0; n < 8; ++n) {
      ushort4 us;
      us.x = f2bf((acc[0][n] + bv.x) * sc);
      us.y = f2bf((acc[1][n] + bv.y) * sc);
      us.z = f2bf((acc[2][n] + bv.z) * sc);
      us.w = f2bf((acc[3][n] + bv.w) * sc);
      *(ushort4*)(dst + (size_t)(b * 4096 + n0 + nb + n) * 128 + pg * 4) = us;
    }
  }
}

// ---------------- 2) MFMA flash attention ----------------
// grid (64 qb, 4 b, 2 split); 256 thr = 4 waves; wave w owns q rows n0+w*16..+15.
// Per KV tile (64 keys): S^T = mfma(A=K,B=Q) -> exp -> sP (bf16) -> Y^T += mfma(A=V^T,B=P^T).
// Outputs UNNORMALIZED partial Y^T[s][b][128][4096] and den[s][b][4096]; zbn combines.
// STATIC LDS 40960 B: sK[64][128], sV[128][64], sP 4x[16][64]. XOR-swizzle in 8-bf16 units.
// Pipelining: next tile's global loads live in registers while current tile computes.
__global__ __launch_bounds__(256, 2) void attn_kernel(
    const unsigned short* __restrict__ Qb, const unsigned short* __restrict__ Kb,
    const unsigned short* __restrict__ Vtb, float* __restrict__ Ytp,
    float* __restrict__ denp) {
  __shared__ unsigned short sm[20480];  // 40960 B static
  const int tid = threadIdx.x;
  const int w = tid >> 6, l = tid & 63;
  const int l15 = l & 15, lh = l >> 4;
  const int b = blockIdx.y, sp = blockIdx.z;
  const int n0 = blockIdx.x * 64;
  const int kvbase = sp * 2048;

  // Q B-fragments, loaded once from global: row n0+w*16+l15, k = lh*8 + ko*32 + j
  bf16x8 qf[4];
  {
    const unsigned short* qrow = Qb + (size_t)(b * 4096 + n0 + w * 16 + l15) * 128 + lh * 8;
#pragma unroll
    for (int ko = 0; ko < 4; ++ko) qf[ko] = *(const bf16x8*)(qrow + ko * 32);
  }
  unsigned short* kb = sm;                      // [64][128]
  unsigned short* vb = sm + 8192;               // [128][64]
  unsigned short* sP = sm + 16384 + w * 1024;   // per-wave [16 q][64 m]

  f32x4 yacc[8];
#pragma unroll
  for (int i = 0; i < 8; ++i) yacc[i] = (f32x4){0.f, 0.f, 0.f, 0.f};
  float den = 0.f;

  const unsigned short* Kbase = Kb + (size_t)(b * 4096 + kvbase) * 128;
  const unsigned short* Vbase = Vtb + (size_t)(b * 128) * 4096 + kvbase;

  uint4 ldK[4], ldV[4];
#define LOADK(IT, KOFF)                                                                   \
  ldK[IT] = *(const uint4*)(Kbase + (size_t)((KOFF) + (((IT)*256 + tid) >> 4)) * 128 +    \
                            (((IT)*256 + tid) & 15) * 8);
#define LOADV(IT, KOFF)                                                                   \
  ldV[IT] = *(const uint4*)(Vbase + (size_t)((((IT)*256 + tid) >> 3)) * 4096 + (KOFF) +   \
                            (((IT)*256 + tid) & 7) * 8);
#pragma unroll
  for (int it = 0; it < 4; ++it) { LOADK(it, 0) LOADV(it, 0) }

  for (int t = 0; t < 32; ++t) {
    __syncthreads();  // all compute on the LDS buffer (iter t-1) done
    // commit staged regs (swizzled: chunk db stored at slot db^(row&7))
#pragma unroll
    for (int it = 0; it < 4; ++it) {
      int c = it * 256 + tid;
      int m = c >> 4, db = c & 15;
      *(uint4*)(kb + m * 128 + ((db ^ (m & 7)) << 3)) = ldK[it];
      int d = c >> 3, mb = c & 7;
      *(uint4*)(vb + d * 64 + ((mb ^ (d & 7)) << 3)) = ldV[it];
    }
    if (t + 1 < 32) {  // issue next tile's global loads (hidden under compute)
      int koff = (t + 1) * 64;
#pragma unroll
      for (int it = 0; it < 4; ++it) { LOADK(it, koff) LOADV(it, koff) }
    }
    __syncthreads();

    // QK^T: S^T[m][q], m-tiles mt=0..3, k over d=128
    f32x4 sacc[4];
#pragma unroll
    for (int mt = 0; mt < 4; ++mt) sacc[mt] = (f32x4){0.f, 0.f, 0.f, 0.f};
#pragma unroll
    for (int ko = 0; ko < 4; ++ko) {
#pragma unroll
      for (int mt = 0; mt < 4; ++mt) {
        int m = mt * 16 + l15;
        bf16x8 ak = *(const bf16x8*)(kb + m * 128 + (((lh + 4 * ko) ^ (m & 7)) << 3));
        sacc[mt] = __builtin_amdgcn_mfma_f32_16x16x32_bf16(ak, qf[ko], sacc[mt], 0, 0, 0);
      }
    }
    // exp (logits bounded ~0.15: no max-sub), pack bf16 -> sP[q][m] (swizzled)
    float rs = 0.f;
#pragma unroll
    for (int mt = 0; mt < 4; ++mt) {
      float e0 = __expf(sacc[mt][0]);
      float e1 = __expf(sacc[mt][1]);
      float e2 = __expf(sacc[mt][2]);
      float e3 = __expf(sacc[mt][3]);
      rs += (e0 + e1) + (e2 + e3);
      ushort4 us;
      us.x = f2bf(e0); us.y = f2bf(e1); us.z = f2bf(e2); us.w = f2bf(e3);
      int mblk = mt * 2 + (lh >> 1);
      *(ushort4*)(sP + l15 * 64 + ((mblk ^ (l15 & 7)) << 3) + (lh & 1) * 4) = us;
    }
    rs += __shfl_xor(rs, 16);
    rs += __shfl_xor(rs, 32);
    den += rs;
    __syncthreads();  // sP write->read ordering (conservative, also covers cross-lane)
    // PV: Y^T += V^T * P^T
#pragma unroll
    for (int ko = 0; ko < 2; ++ko) {
      bf16x8 bp = *(const bf16x8*)(sP + l15 * 64 + (((lh + 4 * ko) ^ (l15 & 7)) << 3));
#pragma unroll
      for (int dt = 0; dt < 8; ++dt) {
        int d = dt * 16 + l15;
        bf16x8 av = *(const bf16x8*)(vb + d * 64 + (((lh + 4 * ko) ^ (d & 7)) << 3));
        yacc[dt] = __builtin_amdgcn_mfma_f32_16x16x32_bf16(av, bp, yacc[dt], 0, 0, 0);
      }
    }
  }
  // epilogue: unnormalized partial Y^T and den
  float* Yt = Ytp + (size_t)(sp * 4 + b) * 128 * 4096;
#pragma unroll
  for (int dt = 0; dt < 8; ++dt)
#pragma unroll
    for (int r = 0; r < 4; ++r)
      Yt[(size_t)(dt * 16 + lh * 4 + r) * 4096 + n0 + w * 16 + l15] = yacc[dt][r];
  if (lh == 0) denp[(size_t)(sp * 4 + b) * 4096 + n0 + w * 16 + l15] = den;
}

// ---------------- 3) z = Wz*y + bz with fused BN partial stats ----------------
// Reads Y^T partials, combines splits, normalizes by den during LDS staging.
__global__ __launch_bounds__(256) void zbn_kernel(
    const float* __restrict__ Ytp, const float* __restrict__ denp,
    const float* __restrict__ Wz, const float* __restrict__ bz,
    float* __restrict__ Z, float* __restrict__ S1, float* __restrict__ S2) {
  __shared__ float sY[128 * 64];  // [p][n]
  __shared__ float sW[64 * 128];  // [c][p]
  const int tid = threadIdx.x;
  const int b = blockIdx.y;
  const int n0 = blockIdx.x * 64;
  // stage Y: (Ya+Yb) / (dena+denb)
#pragma unroll
  for (int it = 0; it < 8; ++it) {
    int c = it * 256 + tid;
    int p = c >> 4, n4 = c & 15;
    size_t o0 = (size_t)(b * 128 + p) * 4096 + n0 + n4 * 4;
    float4 ya = *(const float4*)(Ytp + o0);
    float4 yb = *(const float4*)(Ytp + 2097152 + o0);
    float4 da = *(const float4*)(denp + b * 4096 + n0 + n4 * 4);
    float4 db = *(const float4*)(denp + 16384 + b * 4096 + n0 + n4 * 4);
    float4 r;
    r.x = (ya.x + yb.x) / (da.x + db.x);
    r.y = (ya.y + yb.y) / (da.y + db.y);
    r.z = (ya.z + yb.z) / (da.z + db.z);
    r.w = (ya.w + yb.w) / (da.w + db.w);
    *(float4*)(sY + p * 64 + n4 * 4) = r;
  }
  const int cg = tid >> 4, ng = tid & 15;  // 4c x 4n per thread
  for (int c0 = 0; c0 < 256; c0 += 64) {
    __syncthreads();
#pragma unroll
    for (int it = 0; it < 8; ++it) {  // FULL [64][128]: 2048 float4
      int c = it * 256 + tid;
      int cc = c >> 5, p4 = c & 31;
      *(float4*)(sW + cc * 128 + p4 * 4) =
          *(const float4*)(Wz + (size_t)(c0 + cc) * 128 + p4 * 4);
    }
    __syncthreads();
    float acc[4][4] = {};
    const float* wb0 = sW + cg * 4 * 128;
#pragma unroll 4
    for (int p = 0; p < 128; p += 4) {
      float4 w0 = *(const float4*)(wb0 + p);
      float4 w1 = *(const float4*)(wb0 + 128 + p);
      float4 w2 = *(const float4*)(wb0 + 256 + p);
      float4 w3 = *(const float4*)(wb0 + 384 + p);
      float4 y0 = *(const float4*)(sY + (p + 0) * 64 + ng * 4);
      float4 y1 = *(const float4*)(sY + (p + 1) * 64 + ng * 4);
      float4 y2 = *(const float4*)(sY + (p + 2) * 64 + ng * 4);
      float4 y3 = *(const float4*)(sY + (p + 3) * 64 + ng * 4);
#define ZACC(I, WV)                                                      \
  acc[I][0] += WV.x * y0.x + WV.y * y1.x + WV.z * y2.x + WV.w * y3.x;    \
  acc[I][1] += WV.x * y0.y + WV.y * y1.y + WV.z * y2.y + WV.w * y3.y;    \
  acc[I][2] += WV.x * y0.z + WV.y * y1.z + WV.z * y2.z + WV.w * y3.z;    \
  acc[I][3] += WV.x * y0.w + WV.y * y1.w + WV.z * y2.w + WV.w * y3.w;
      ZACC(0, w0) ZACC(1, w1) ZACC(2, w2) ZACC(3, w3)
    }
#pragma unroll
    for (int i = 0; i < 4; ++i) {
      int c = c0 + cg * 4 + i;
      float bzv = bz[c];
      float z0 = acc[i][0] + bzv, z1 = acc[i][1] + bzv;
      float z2 = acc[i][2] + bzv, z3 = acc[i][3] + bzv;
      *(float4*)(Z + (size_t)(b * 256 + c) * 4096 + n0 + ng * 4) =
          make_float4(z0, z1, z2, z3);
      float s1 = (z0 + z1) + (z2 + z3);
      float s2 = (z0 * z0 + z1 * z1) + (z2 * z2 + z3 * z3);
#pragma unroll
      for (int m = 1; m < 16; m <<= 1) {
        s1 += __shfl_xor(s1, m);
        s2 += __shfl_xor(s2, m);
      }
      if (ng == 0) {
        atomicAdd(&S1[c], s1);
        atomicAdd(&S2[c], s2);
      }
    }
  }
}

// ---------------- 4) BN finalize ----------------
__global__ void bnfin_kernel(const float* __restrict__ S1, const float* __restrict__ S2,
                             const float* __restrict__ gamma, const float* __restrict__ beta,
                             float* __restrict__ Scale, float* __restrict__ Shift) {
  int c = threadIdx.x;
  const float inv_cnt = 1.0f / 16384.0f;  // B*N
  float mean = S1[c] * inv_cnt;
  float var = S2[c] * inv_cnt - mean * mean;
  var = fmaxf(var, 0.0f);
  float inv = rsqrtf(var + 1e-5f);
  float sc = gamma[c] * inv;
  Scale[c] = sc;
  Shift[c] = beta[c] - mean * sc;
}

// ---------------- 5) out = z*scale + shift + x ----------------
__global__ __launch_bounds__(256) void out_kernel(
    const float* __restrict__ Z, const float* __restrict__ x,
    const float* __restrict__ Scale, const float* __restrict__ Shift,
    float* __restrict__ out) {
  int i4 = blockIdx.x * 256 + threadIdx.x;
  int flat = i4 << 2;
  int c = (flat >> 12) & 255;
  float4 z = *(const float4*)(Z + flat);
  float4 xv = *(const float4*)(x + flat);
  float sc = Scale[c], sh = Shift[c];
  float4 o;
  o.x = z.x * sc + sh + xv.x;
  o.y = z.y * sc + sh + xv.y;
  o.z = z.z * sc + sh + xv.z;
  o.w = z.w * sc + sh + xv.w;
  *(float4*)(out + flat) = o;
}

extern "C" void kernel_launch(void* const* d_in, const int* in_sizes, int n_in,
                              void* d_out, int out_size, void* d_ws, size_t ws_size,
                              hipStream_t stream) {
  (void)in_sizes; (void)n_in; (void)out_size; (void)ws_size;
  const float* x = (const float*)d_in[0];
  const float* Wt = (const float*)d_in[1];
  const float* bt = (const float*)d_in[2];
  const float* Wp = (const float*)d_in[3];
  const float* bp = (const float*)d_in[4];
  const float* Wg = (const float*)d_in[5];
  const float* bg = (const float*)d_in[6];
  const float* Wz = (const float*)d_in[7];
  const float* bz = (const float*)d_in[8];
  const float* gamma = (const float*)d_in[9];
  const float* beta = (const float*)d_in[10];

  unsigned short* Qb = (unsigned short*)d_ws;        // 2,097,152 bf16 (4 MB)
  unsigned short* Kb = Qb + 2097152;                 // 4 MB
  unsigned short* Vtb = Kb + 2097152;                // 4 MB (transposed)
  float* fbase = (float*)(Vtb + 2097152);
  float* Ytp = fbase;                                // 2 x 2,097,152 f32 (16 MB)
  float* denp = Ytp + 4194304;                       // 2 x 16384
  float* Z = denp + 32768;                           // 4,194,304 f32 (16 MB)
  float* S1 = Z + 4194304;                           // 256
  float* S2 = S1 + 256;                              // 256
  float* Scale = S2 + 256;                           // 256
  float* Shift = Scale + 256;                        // 256

  hipMemsetAsync(S1, 0, 512 * sizeof(float), stream);

  proj_kernel<<<dim3(64, 3, 4), 256, 0, stream>>>(x, Wt, bt, Wp, bp, Wg, bg, Qb, Kb, Vtb);
  attn_kernel<<<dim3(64, 4, 2), 256, 0, stream>>>(Qb, Kb, Vtb, Ytp, denp);
  zbn_kernel<<<dim3(64, 4), 256, 0, stream>>>(Ytp, denp, Wz, bz, Z, S1, S2);
  bnfin_kernel<<<1, 256, 0, stream>>>(S1, S2, gamma, beta, Scale, Shift);
  out_kernel<<<4096, 256, 0, stream>>>(Z, x, Scale, Shift, (float*)d_out);
}

// Round 5
// 195.673 us; speedup vs baseline: 4.0673x; 1.4880x over previous
//
#include <hip/hip_runtime.h>

// NonLocal block: B=4, C=256, P=128, H=W=64, N=4096.
// proj(Q,K bf16 [b][n][p]; V^T bf16 [b][p][n]) -> MFMA flash-attn (no-max softmax,
// S^T=mfma(K,Q), Y^T=mfma(V^T,P^T), kv-split=4, global_load_lds staging with
// pre-swizzled global source) -> zbn (combine 4 bf16 partials, z=Wz*y, fused BN
// stats) -> BN finalize -> elementwise out.
// R5: attn was latency-bound (2 blocks/CU, Occ 18%) + spilling ldK/ldV (WRITE_SIZE
// 191MB vs 16MB legit). Fix: gload_lds direct staging (no reg round-trip), split=4
// (4 blocks/CU, LDS 4x40960=160KiB exactly), bf16 partials, 2 barriers/tile.

#define SCALE_ 0.08838834764831845f  // 1/sqrt(128)

typedef __bf16 bf16x8 __attribute__((ext_vector_type(8)));
typedef float f32x4 __attribute__((ext_vector_type(4)));
typedef unsigned short ushort8v __attribute__((ext_vector_type(8)));

__device__ inline unsigned short f2bf(float f) {  // RNE float->bf16
  unsigned int u = __float_as_uint(f);
  u += 0x7fffu + ((u >> 16) & 1u);
  return (unsigned short)(u >> 16);
}
__device__ inline float bflo(unsigned int u) { return __uint_as_float(u << 16); }
__device__ inline float bfhi(unsigned int u) { return __uint_as_float(u & 0xffff0000u); }

// async global->LDS, 16B per lane; LDS dest = wave-uniform base + lane*16 (linear).
__device__ inline void gl16(const unsigned short* g, unsigned short* l) {
  __builtin_amdgcn_global_load_lds(
      (const __attribute__((address_space(1))) unsigned int*)(g),
      (__attribute__((address_space(3))) unsigned int*)(l), 16, 0, 0);
}

// ---------------- 1) projections ----------------
// Q[b][n][p] = (Wt x + bt) * SCALE_  (bf16)
// K[b][n][p] = Wp x + bp             (bf16)
// Vt[b][p][n] = Wg x + bg            (bf16, transposed)
__global__ __launch_bounds__(256) void proj_kernel(
    const float* __restrict__ x,
    const float* __restrict__ Wt, const float* __restrict__ bt,
    const float* __restrict__ Wp, const float* __restrict__ bp,
    const float* __restrict__ Wg, const float* __restrict__ bg,
    unsigned short* __restrict__ Qb, unsigned short* __restrict__ Kb,
    unsigned short* __restrict__ Vtb) {
  __shared__ float sW[128 * 64];  // [p][c4 ^ ((p>>2)&7)] float4-col swizzle
  __shared__ float sX[64 * 64];   // [c][n]
  const int tid = threadIdx.x;
  const int n0 = blockIdx.x * 64;
  const int sel = blockIdx.y;  // 0=t->Q, 1=p->K, 2=g->Vt
  const int b = blockIdx.z;
  const float* W = sel == 0 ? Wt : (sel == 1 ? Wp : Wg);
  const float* bias = sel == 0 ? bt : (sel == 1 ? bp : bg);
  const int pg = tid & 31, ng = tid >> 5;  // thread tile: 4p x 8n
  const int nb = ng * 8;
  float acc[4][8];
#pragma unroll
  for (int i = 0; i < 4; ++i)
#pragma unroll
    for (int n = 0; n < 8; ++n) acc[i][n] = 0.f;

  for (int c0 = 0; c0 < 256; c0 += 64) {
    __syncthreads();
#pragma unroll
    for (int it = 0; it < 8; ++it) {
      int e4 = it * 256 + tid;
      int p = e4 >> 4, cQ = e4 & 15;
      float4 v = *(const float4*)(W + p * 256 + c0 + cQ * 4);
      *(float4*)(sW + p * 64 + ((cQ ^ ((p >> 2) & 7)) << 2)) = v;
    }
#pragma unroll
    for (int it = 0; it < 4; ++it) {
      int e4 = it * 256 + tid;
      int cc = e4 >> 4, nn4 = e4 & 15;
      float4 v = *(const float4*)(x + (size_t)(b * 256 + c0 + cc) * 4096 + n0 + nn4 * 4);
      *(float4*)(sX + cc * 64 + nn4 * 4) = v;
    }
    __syncthreads();
    const int sw = pg & 7;
#pragma unroll 2
    for (int c4 = 0; c4 < 16; ++c4) {
      int wo = ((c4 ^ sw) << 2);
      const float* wbse = sW + pg * 256 + wo;
      float4 w0 = *(const float4*)(wbse);
      float4 w1 = *(const float4*)(wbse + 64);
      float4 w2 = *(const float4*)(wbse + 128);
      float4 w3 = *(const float4*)(wbse + 192);
#define PROJ_CC(CMP, XROW)                                                               \
  {                                                                                      \
    const float* xr = sX + (XROW) * 64 + nb;                                             \
    float4 xa = *(const float4*)(xr);                                                    \
    float4 xb = *(const float4*)(xr + 4);                                                \
    acc[0][0] += w0.CMP * xa.x; acc[0][1] += w0.CMP * xa.y;                              \
    acc[0][2] += w0.CMP * xa.z; acc[0][3] += w0.CMP * xa.w;                              \
    acc[0][4] += w0.CMP * xb.x; acc[0][5] += w0.CMP * xb.y;                              \
    acc[0][6] += w0.CMP * xb.z; acc[0][7] += w0.CMP * xb.w;                              \
    acc[1][0] += w1.CMP * xa.x; acc[1][1] += w1.CMP * xa.y;                              \
    acc[1][2] += w1.CMP * xa.z; acc[1][3] += w1.CMP * xa.w;                              \
    acc[1][4] += w1.CMP * xb.x; acc[1][5] += w1.CMP * xb.y;                              \
    acc[1][6] += w1.CMP * xb.z; acc[1][7] += w1.CMP * xb.w;                              \
    acc[2][0] += w2.CMP * xa.x; acc[2][1] += w2.CMP * xa.y;                              \
    acc[2][2] += w2.CMP * xa.z; acc[2][3] += w2.CMP * xa.w;                              \
    acc[2][4] += w2.CMP * xb.x; acc[2][5] += w2.CMP * xb.y;                              \
    acc[2][6] += w2.CMP * xb.z; acc[2][7] += w2.CMP * xb.w;                              \
    acc[3][0] += w3.CMP * xa.x; acc[3][1] += w3.CMP * xa.y;                              \
    acc[3][2] += w3.CMP * xa.z; acc[3][3] += w3.CMP * xa.w;                              \
    acc[3][4] += w3.CMP * xb.x; acc[3][5] += w3.CMP * xb.y;                              \
    acc[3][6] += w3.CMP * xb.z; acc[3][7] += w3.CMP * xb.w;                              \
  }
      PROJ_CC(x, c4 * 4 + 0)
      PROJ_CC(y, c4 * 4 + 1)
      PROJ_CC(z, c4 * 4 + 2)
      PROJ_CC(w, c4 * 4 + 3)
    }
  }
  float4 bv = *(const float4*)(bias + pg * 4);
  const float* bvf = (const float*)&bv;
  if (sel == 2) {
    // V: transposed write [b][p][n], 8 contiguous n per p-row
#pragma unroll
    for (int i = 0; i < 4; ++i) {
      ushort8v us;
#pragma unroll
      for (int n = 0; n < 8; ++n) us[n] = f2bf(acc[i][n] + bvf[i]);
      *(ushort8v*)(Vtb + (size_t)(b * 128 + pg * 4 + i) * 4096 + n0 + nb) = us;
    }
  } else {
    const float sc = sel == 0 ? SCALE_ : 1.0f;
    unsigned short* dst = sel == 0 ? Qb : Kb;
#pragma unroll
    for (int n = 0; n < 8; ++n) {
      ushort4 us;
      us.x = f2bf((acc[0][n] + bv.x) * sc);
      us.y = f2bf((acc[1][n] + bv.y) * sc);
      us.z = f2bf((acc[2][n] + bv.z) * sc);
      us.w = f2bf((acc[3][n] + bv.w) * sc);
      *(ushort4*)(dst + (size_t)(b * 4096 + n0 + nb + n) * 128 + pg * 4) = us;
    }
  }
}

// ---------------- 2) MFMA flash attention ----------------
// grid (64 qb, 4 b, 4 split); 256 thr = 4 waves; wave w owns q rows n0+w*16..+15.
// Per KV tile (64 keys): gload_lds K,V (pre-swizzled global source, linear LDS dest)
// -> sync (drains vmcnt) -> S^T=mfma(K,Q) -> exp -> sP(bf16, wave-private, no barrier)
// -> Y^T += mfma(V^T,P^T). Outputs UNNORMALIZED bf16 partial Y^T and f32 den.
// STATIC LDS 40960 B (kb[64][128], vb[128][64], sP 4x[16][64]); 4 blocks/CU = 160KiB.
__global__ __launch_bounds__(256, 4) void attn_kernel(
    const unsigned short* __restrict__ Qb, const unsigned short* __restrict__ Kb,
    const unsigned short* __restrict__ Vtb, unsigned short* __restrict__ Ytp,
    float* __restrict__ denp) {
  __shared__ unsigned short sm[20480];  // 40960 B static
  const int tid = threadIdx.x;
  const int w = tid >> 6, l = tid & 63;
  const int l15 = l & 15, lh = l >> 4;
  const int b = blockIdx.y, sp = blockIdx.z;
  const int n0 = blockIdx.x * 64;
  const int kvbase = sp * 1024;  // 4 splits x 1024 keys

  // Q B-fragments, loaded once from global: row n0+w*16+l15, k = lh*8 + ko*32 + j
  bf16x8 qf[4];
  {
    const unsigned short* qrow = Qb + (size_t)(b * 4096 + n0 + w * 16 + l15) * 128 + lh * 8;
#pragma unroll
    for (int ko = 0; ko < 4; ++ko) qf[ko] = *(const bf16x8*)(qrow + ko * 32);
  }
  unsigned short* kb = sm;                      // [64][128] (chunk slot s holds global chunk s^(m&7))
  unsigned short* vb = sm + 8192;               // [128][64] (slot s holds chunk s^(d&7))
  unsigned short* sP = sm + 16384 + w * 1024;   // per-wave [16 q][64 m]

  f32x4 yacc[8];
#pragma unroll
  for (int i = 0; i < 8; ++i) yacc[i] = (f32x4){0.f, 0.f, 0.f, 0.f};
  float den = 0.f;

  const unsigned short* Kbase = Kb + (size_t)(b * 4096 + kvbase) * 128;
  const unsigned short* Vbase = Vtb + (size_t)(b * 128) * 4096 + kvbase;

  // per-lane source sub-offsets (constant over tiles)
  const int kmrow_off = l >> 4;                 // row within 4-row group
  const int vdrow_off = l >> 3;                 // row within 8-row group

  for (int t = 0; t < 16; ++t) {
    const int koff = t * 64;
    __syncthreads();  // all waves done reading kb/vb from prev tile
    // stage K,V via async DMA; swizzle folded into the GLOBAL address
#pragma unroll
    for (int it = 0; it < 4; ++it) {
      int mrow = w * 16 + it * 4 + kmrow_off;  // tile-local K row
      gl16(Kbase + (size_t)(koff + mrow) * 128 + (((l & 15) ^ (mrow & 7)) << 3),
           kb + (w * 16 + it * 4) * 128);
      int drow = w * 32 + it * 8 + vdrow_off;  // V^T row (= p dim)
      gl16(Vbase + (size_t)drow * 4096 + koff + (((l & 7) ^ (drow & 7)) << 3),
           vb + (w * 32 + it * 8) * 64);
    }
    __syncthreads();  // drains vmcnt(0): LDS tiles ready

    // QK^T: S^T[m][q], m-tiles mt=0..3, k over d=128
    f32x4 sacc[4];
#pragma unroll
    for (int mt = 0; mt < 4; ++mt) sacc[mt] = (f32x4){0.f, 0.f, 0.f, 0.f};
#pragma unroll
    for (int ko = 0; ko < 4; ++ko) {
#pragma unroll
      for (int mt = 0; mt < 4; ++mt) {
        int m = mt * 16 + l15;
        bf16x8 ak = *(const bf16x8*)(kb + m * 128 + (((lh + 4 * ko) ^ (m & 7)) << 3));
        sacc[mt] = __builtin_amdgcn_mfma_f32_16x16x32_bf16(ak, qf[ko], sacc[mt], 0, 0, 0);
      }
    }
    // exp (logits bounded ~0.15: no max-sub), pack bf16 -> sP[q][m] (swizzled)
    float rs = 0.f;
#pragma unroll
    for (int mt = 0; mt < 4; ++mt) {
      float e0 = __expf(sacc[mt][0]);
      float e1 = __expf(sacc[mt][1]);
      float e2 = __expf(sacc[mt][2]);
      float e3 = __expf(sacc[mt][3]);
      rs += (e0 + e1) + (e2 + e3);
      ushort4 us;
      us.x = f2bf(e0); us.y = f2bf(e1); us.z = f2bf(e2); us.w = f2bf(e3);
      int mblk = mt * 2 + (lh >> 1);
      *(ushort4*)(sP + l15 * 64 + ((mblk ^ (l15 & 7)) << 3) + (lh & 1) * 4) = us;
    }
    rs += __shfl_xor(rs, 16);
    rs += __shfl_xor(rs, 32);
    den += rs;
    // sP is wave-private: program order + compiler lgkmcnt suffice (no barrier)
    // PV: Y^T += V^T * P^T
#pragma unroll
    for (int ko = 0; ko < 2; ++ko) {
      bf16x8 bp = *(const bf16x8*)(sP + l15 * 64 + (((lh + 4 * ko) ^ (l15 & 7)) << 3));
#pragma unroll
      for (int dt = 0; dt < 8; ++dt) {
        int d = dt * 16 + l15;
        bf16x8 av = *(const bf16x8*)(vb + d * 64 + (((lh + 4 * ko) ^ (d & 7)) << 3));
        yacc[dt] = __builtin_amdgcn_mfma_f32_16x16x32_bf16(av, bp, yacc[dt], 0, 0, 0);
      }
    }
  }
  // epilogue: unnormalized bf16 partial Y^T and f32 den
  unsigned short* Yt = Ytp + (size_t)(sp * 4 + b) * 524288;
#pragma unroll
  for (int dt = 0; dt < 8; ++dt)
#pragma unroll
    for (int r = 0; r < 4; ++r)
      Yt[(size_t)(dt * 16 + lh * 4 + r) * 4096 + n0 + w * 16 + l15] = f2bf(yacc[dt][r]);
  if (lh == 0) denp[(size_t)(sp * 4 + b) * 4096 + n0 + w * 16 + l15] = den;
}

// ---------------- 3) z = Wz*y + bz with fused BN partial stats ----------------
// Combines 4 bf16 Y^T partials, normalizes by combined den during LDS staging.
__global__ __launch_bounds__(256) void zbn_kernel(
    const unsigned short* __restrict__ Ytp, const float* __restrict__ denp,
    const float* __restrict__ Wz, const float* __restrict__ bz,
    float* __restrict__ Z, float* __restrict__ S1, float* __restrict__ S2) {
  __shared__ float sY[128 * 64];  // [p][n]
  __shared__ float sW[64 * 128];  // [c][p]
  __shared__ float sDen[64];      // 1 / sum_sp den
  const int tid = threadIdx.x;
  const int b = blockIdx.y;
  const int n0 = blockIdx.x * 64;
  if (tid < 64) {
    float s = 0.f;
#pragma unroll
    for (int sp = 0; sp < 4; ++sp) s += denp[sp * 16384 + b * 4096 + n0 + tid];
    sDen[tid] = 1.0f / s;
  }
  __syncthreads();
  // stage Y: (sum of 4 bf16 partials) * sDen  -> sY[p][n], 8-elem chunks
#pragma unroll
  for (int it = 0; it < 4; ++it) {
    int c = it * 256 + tid;
    int p = c >> 3, n8 = c & 7;
    size_t o = (size_t)(b * 128 + p) * 4096 + n0 + n8 * 8;
    float a0 = 0, a1 = 0, a2 = 0, a3 = 0, a4 = 0, a5 = 0, a6 = 0, a7 = 0;
#pragma unroll
    for (int sp = 0; sp < 4; ++sp) {
      uint4 v = *(const uint4*)(Ytp + (size_t)sp * 2097152 + o);
      a0 += bflo(v.x); a1 += bfhi(v.x);
      a2 += bflo(v.y); a3 += bfhi(v.y);
      a4 += bflo(v.z); a5 += bfhi(v.z);
      a6 += bflo(v.w); a7 += bfhi(v.w);
    }
    float* dst = sY + p * 64 + n8 * 8;
    const float* dn = sDen + n8 * 8;
    dst[0] = a0 * dn[0]; dst[1] = a1 * dn[1]; dst[2] = a2 * dn[2]; dst[3] = a3 * dn[3];
    dst[4] = a4 * dn[4]; dst[5] = a5 * dn[5]; dst[6] = a6 * dn[6]; dst[7] = a7 * dn[7];
  }
  const int cg = tid >> 4, ng = tid & 15;  // 4c x 4n per thread
  for (int c0 = 0; c0 < 256; c0 += 64) {
    __syncthreads();
#pragma unroll
    for (int it = 0; it < 8; ++it) {  // FULL [64][128]: 2048 float4
      int c = it * 256 + tid;
      int cc = c >> 5, p4 = c & 31;
      *(float4*)(sW + cc * 128 + p4 * 4) =
          *(const float4*)(Wz + (size_t)(c0 + cc) * 128 + p4 * 4);
    }
    __syncthreads();
    float acc[4][4] = {};
    const float* wb0 = sW + cg * 4 * 128;
#pragma unroll 4
    for (int p = 0; p < 128; p += 4) {
      float4 w0 = *(const float4*)(wb0 + p);
      float4 w1 = *(const float4*)(wb0 + 128 + p);
      float4 w2 = *(const float4*)(wb0 + 256 + p);
      float4 w3 = *(const float4*)(wb0 + 384 + p);
      float4 y0 = *(const float4*)(sY + (p + 0) * 64 + ng * 4);
      float4 y1 = *(const float4*)(sY + (p + 1) * 64 + ng * 4);
      float4 y2 = *(const float4*)(sY + (p + 2) * 64 + ng * 4);
      float4 y3 = *(const float4*)(sY + (p + 3) * 64 + ng * 4);
#define D4(A, Q, K) A += Q.x * K.x; A += Q.y * K.y; A += Q.z * K.z; A += Q.w * K.w;
#define ZACC(I, WV)                                                      \
  acc[I][0] += WV.x * y0.x + WV.y * y1.x + WV.z * y2.x + WV.w * y3.x;    \
  acc[I][1] += WV.x * y0.y + WV.y * y1.y + WV.z * y2.y + WV.w * y3.y;    \
  acc[I][2] += WV.x * y0.z + WV.y * y1.z + WV.z * y2.z + WV.w * y3.z;    \
  acc[I][3] += WV.x * y0.w + WV.y * y1.w + WV.z * y2.w + WV.w * y3.w;
      ZACC(0, w0) ZACC(1, w1) ZACC(2, w2) ZACC(3, w3)
    }
#pragma unroll
    for (int i = 0; i < 4; ++i) {
      int c = c0 + cg * 4 + i;
      float bzv = bz[c];
      float z0 = acc[i][0] + bzv, z1 = acc[i][1] + bzv;
      float z2 = acc[i][2] + bzv, z3 = acc[i][3] + bzv;
      *(float4*)(Z + (size_t)(b * 256 + c) * 4096 + n0 + ng * 4) =
          make_float4(z0, z1, z2, z3);
      float s1 = (z0 + z1) + (z2 + z3);
      float s2 = (z0 * z0 + z1 * z1) + (z2 * z2 + z3 * z3);
#pragma unroll
      for (int m = 1; m < 16; m <<= 1) {
        s1 += __shfl_xor(s1, m);
        s2 += __shfl_xor(s2, m);
      }
      if (ng == 0) {
        atomicAdd(&S1[c], s1);
        atomicAdd(&S2[c], s2);
      }
    }
  }
}

// ---------------- 4) BN finalize ----------------
__global__ void bnfin_kernel(const float* __restrict__ S1, const float* __restrict__ S2,
                             const float* __restrict__ gamma, const float* __restrict__ beta,
                             float* __restrict__ Scale, float* __restrict__ Shift) {
  int c = threadIdx.x;
  const float inv_cnt = 1.0f / 16384.0f;  // B*N
  float mean = S1[c] * inv_cnt;
  float var = S2[c] * inv_cnt - mean * mean;
  var = fmaxf(var, 0.0f);
  float inv = rsqrtf(var + 1e-5f);
  float sc = gamma[c] * inv;
  Scale[c] = sc;
  Shift[c] = beta[c] - mean * sc;
}

// ---------------- 5) out = z*scale + shift + x ----------------
__global__ __launch_bounds__(256) void out_kernel(
    const float* __restrict__ Z, const float* __restrict__ x,
    const float* __restrict__ Scale, const float* __restrict__ Shift,
    float* __restrict__ out) {
  int i4 = blockIdx.x * 256 + threadIdx.x;
  int flat = i4 << 2;
  int c = (flat >> 12) & 255;
  float4 z = *(const float4*)(Z + flat);
  float4 xv = *(const float4*)(x + flat);
  float sc = Scale[c], sh = Shift[c];
  float4 o;
  o.x = z.x * sc + sh + xv.x;
  o.y = z.y * sc + sh + xv.y;
  o.z = z.z * sc + sh + xv.z;
  o.w = z.w * sc + sh + xv.w;
  *(float4*)(out + flat) = o;
}

extern "C" void kernel_launch(void* const* d_in, const int* in_sizes, int n_in,
                              void* d_out, int out_size, void* d_ws, size_t ws_size,
                              hipStream_t stream) {
  (void)in_sizes; (void)n_in; (void)out_size; (void)ws_size;
  const float* x = (const float*)d_in[0];
  const float* Wt = (const float*)d_in[1];
  const float* bt = (const float*)d_in[2];
  const float* Wp = (const float*)d_in[3];
  const float* bp = (const float*)d_in[4];
  const float* Wg = (const float*)d_in[5];
  const float* bg = (const float*)d_in[6];
  const float* Wz = (const float*)d_in[7];
  const float* bz = (const float*)d_in[8];
  const float* gamma = (const float*)d_in[9];
  const float* beta = (const float*)d_in[10];

  unsigned short* Qb = (unsigned short*)d_ws;        // 2,097,152 bf16 (4 MB)
  unsigned short* Kb = Qb + 2097152;                 // 4 MB
  unsigned short* Vtb = Kb + 2097152;                // 4 MB (transposed)
  unsigned short* Ytp = Vtb + 2097152;               // 4 x 2,097,152 bf16 partials (16 MB)
  float* denp = (float*)(Ytp + 8388608);             // 4 x 16384 f32
  float* Z = denp + 65536;                           // 4,194,304 f32 (16 MB)
  float* S1 = Z + 4194304;                           // 256
  float* S2 = S1 + 256;                              // 256
  float* Scale = S2 + 256;                           // 256
  float* Shift = Scale + 256;                        // 256

  hipMemsetAsync(S1, 0, 512 * sizeof(float), stream);

  proj_kernel<<<dim3(64, 3, 4), 256, 0, stream>>>(x, Wt, bt, Wp, bp, Wg, bg, Qb, Kb, Vtb);
  attn_kernel<<<dim3(64, 4, 4), 256, 0, stream>>>(Qb, Kb, Vtb, Ytp, denp);
  zbn_kernel<<<dim3(64, 4), 256, 0, stream>>>(Ytp, denp, Wz, bz, Z, S1, S2);
  bnfin_kernel<<<1, 256, 0, stream>>>(S1, S2, gamma, beta, Scale, Shift);
  out_kernel<<<4096, 256, 0, stream>>>(Z, x, Scale, Shift, (float*)d_out);
}

// Round 6
// 162.631 us; speedup vs baseline: 4.8937x; 1.2032x over previous
//
#include <hip/hip_runtime.h>

// NonLocal block: B=4, C=256, P=128, H=W=64, N=4096.
// proj(Q,K bf16 [b][n][p]; V^T bf16 [b][p][n]) -> MFMA flash-attn (no-max softmax,
// S^T=mfma(K,Q), Y^T=mfma(V^T,P^T), kv-split=4, gload_lds staging, bf16 partials
// Y[n][p]) -> zbn v2 (MFMA: combine partials -> bf16 LDS, z=Wz*y via 16x16x32,
// fused BN stats; grid x4 c-split, 4 blocks/CU) -> BN finalize -> elementwise out.
// R6: zbn was latency-starved (1 block/CU, Occ 8.9%, VALU 12%). MFMA + 1024 blocks.

#define SCALE_ 0.08838834764831845f  // 1/sqrt(128)

typedef __bf16 bf16x8 __attribute__((ext_vector_type(8)));
typedef float f32x4 __attribute__((ext_vector_type(4)));
typedef unsigned short ushort8v __attribute__((ext_vector_type(8)));

__device__ inline unsigned short f2bf(float f) {  // RNE float->bf16
  unsigned int u = __float_as_uint(f);
  u += 0x7fffu + ((u >> 16) & 1u);
  return (unsigned short)(u >> 16);
}
__device__ inline float bflo(unsigned int u) { return __uint_as_float(u << 16); }
__device__ inline float bfhi(unsigned int u) { return __uint_as_float(u & 0xffff0000u); }

// async global->LDS, 16B per lane; LDS dest = wave-uniform base + lane*16 (linear).
__device__ inline void gl16(const unsigned short* g, unsigned short* l) {
  __builtin_amdgcn_global_load_lds(
      (const __attribute__((address_space(1))) unsigned int*)(g),
      (__attribute__((address_space(3))) unsigned int*)(l), 16, 0, 0);
}

// ---------------- 1) projections ----------------
// Q[b][n][p] = (Wt x + bt) * SCALE_  (bf16)
// K[b][n][p] = Wp x + bp             (bf16)
// Vt[b][p][n] = Wg x + bg            (bf16, transposed)
__global__ __launch_bounds__(256) void proj_kernel(
    const float* __restrict__ x,
    const float* __restrict__ Wt, const float* __restrict__ bt,
    const float* __restrict__ Wp, const float* __restrict__ bp,
    const float* __restrict__ Wg, const float* __restrict__ bg,
    unsigned short* __restrict__ Qb, unsigned short* __restrict__ Kb,
    unsigned short* __restrict__ Vtb) {
  __shared__ float sW[128 * 64];  // [p][c4 ^ ((p>>2)&7)] float4-col swizzle
  __shared__ float sX[64 * 64];   // [c][n]
  const int tid = threadIdx.x;
  const int n0 = blockIdx.x * 64;
  const int sel = blockIdx.y;  // 0=t->Q, 1=p->K, 2=g->Vt
  const int b = blockIdx.z;
  const float* W = sel == 0 ? Wt : (sel == 1 ? Wp : Wg);
  const float* bias = sel == 0 ? bt : (sel == 1 ? bp : bg);
  const int pg = tid & 31, ng = tid >> 5;  // thread tile: 4p x 8n
  const int nb = ng * 8;
  float acc[4][8];
#pragma unroll
  for (int i = 0; i < 4; ++i)
#pragma unroll
    for (int n = 0; n < 8; ++n) acc[i][n] = 0.f;

  for (int c0 = 0; c0 < 256; c0 += 64) {
    __syncthreads();
#pragma unroll
    for (int it = 0; it < 8; ++it) {
      int e4 = it * 256 + tid;
      int p = e4 >> 4, cQ = e4 & 15;
      float4 v = *(const float4*)(W + p * 256 + c0 + cQ * 4);
      *(float4*)(sW + p * 64 + ((cQ ^ ((p >> 2) & 7)) << 2)) = v;
    }
#pragma unroll
    for (int it = 0; it < 4; ++it) {
      int e4 = it * 256 + tid;
      int cc = e4 >> 4, nn4 = e4 & 15;
      float4 v = *(const float4*)(x + (size_t)(b * 256 + c0 + cc) * 4096 + n0 + nn4 * 4);
      *(float4*)(sX + cc * 64 + nn4 * 4) = v;
    }
    __syncthreads();
    const int sw = pg & 7;
#pragma unroll 2
    for (int c4 = 0; c4 < 16; ++c4) {
      int wo = ((c4 ^ sw) << 2);
      const float* wbse = sW + pg * 256 + wo;
      float4 w0 = *(const float4*)(wbse);
      float4 w1 = *(const float4*)(wbse + 64);
      float4 w2 = *(const float4*)(wbse + 128);
      float4 w3 = *(const float4*)(wbse + 192);
#define PROJ_CC(CMP, XROW)                                                               \
  {                                                                                      \
    const float* xr = sX + (XROW) * 64 + nb;                                             \
    float4 xa = *(const float4*)(xr);                                                    \
    float4 xb = *(const float4*)(xr + 4);                                                \
    acc[0][0] += w0.CMP * xa.x; acc[0][1] += w0.CMP * xa.y;                              \
    acc[0][2] += w0.CMP * xa.z; acc[0][3] += w0.CMP * xa.w;                              \
    acc[0][4] += w0.CMP * xb.x; acc[0][5] += w0.CMP * xb.y;                              \
    acc[0][6] += w0.CMP * xb.z; acc[0][7] += w0.CMP * xb.w;                              \
    acc[1][0] += w1.CMP * xa.x; acc[1][1] += w1.CMP * xa.y;                              \
    acc[1][2] += w1.CMP * xa.z; acc[1][3] += w1.CMP * xa.w;                              \
    acc[1][4] += w1.CMP * xb.x; acc[1][5] += w1.CMP * xb.y;                              \
    acc[1][6] += w1.CMP * xb.z; acc[1][7] += w1.CMP * xb.w;                              \
    acc[2][0] += w2.CMP * xa.x; acc[2][1] += w2.CMP * xa.y;                              \
    acc[2][2] += w2.CMP * xa.z; acc[2][3] += w2.CMP * xa.w;                              \
    acc[2][4] += w2.CMP * xb.x; acc[2][5] += w2.CMP * xb.y;                              \
    acc[2][6] += w2.CMP * xb.z; acc[2][7] += w2.CMP * xb.w;                              \
    acc[3][0] += w3.CMP * xa.x; acc[3][1] += w3.CMP * xa.y;                              \
    acc[3][2] += w3.CMP * xa.z; acc[3][3] += w3.CMP * xa.w;                              \
    acc[3][4] += w3.CMP * xb.x; acc[3][5] += w3.CMP * xb.y;                              \
    acc[3][6] += w3.CMP * xb.z; acc[3][7] += w3.CMP * xb.w;                              \
  }
      PROJ_CC(x, c4 * 4 + 0)
      PROJ_CC(y, c4 * 4 + 1)
      PROJ_CC(z, c4 * 4 + 2)
      PROJ_CC(w, c4 * 4 + 3)
    }
  }
  float4 bv = *(const float4*)(bias + pg * 4);
  const float* bvf = (const float*)&bv;
  if (sel == 2) {
    // V: transposed write [b][p][n], 8 contiguous n per p-row
#pragma unroll
    for (int i = 0; i < 4; ++i) {
      ushort8v us;
#pragma unroll
      for (int n = 0; n < 8; ++n) us[n] = f2bf(acc[i][n] + bvf[i]);
      *(ushort8v*)(Vtb + (size_t)(b * 128 + pg * 4 + i) * 4096 + n0 + nb) = us;
    }
  } else {
    const float sc = sel == 0 ? SCALE_ : 1.0f;
    unsigned short* dst = sel == 0 ? Qb : Kb;
#pragma unroll
    for (int n = 0; n < 8; ++n) {
      ushort4 us;
      us.x = f2bf((acc[0][n] + bv.x) * sc);
      us.y = f2bf((acc[1][n] + bv.y) * sc);
      us.z = f2bf((acc[2][n] + bv.z) * sc);
      us.w = f2bf((acc[3][n] + bv.w) * sc);
      *(ushort4*)(dst + (size_t)(b * 4096 + n0 + nb + n) * 128 + pg * 4) = us;
    }
  }
}

// ---------------- 2) MFMA flash attention ----------------
// grid (64 qb, 4 b, 4 split); 256 thr = 4 waves; wave w owns q rows n0+w*16..+15.
// Per KV tile (64 keys): gload_lds K,V (pre-swizzled global source, linear LDS dest)
// -> sync -> S^T=mfma(K,Q) -> exp -> sP(bf16, wave-private) -> Y^T += mfma(V^T,P^T).
// Outputs UNNORMALIZED bf16 partial Y[n][p] (row-major!) and f32 den.
__global__ __launch_bounds__(256, 4) void attn_kernel(
    const unsigned short* __restrict__ Qb, const unsigned short* __restrict__ Kb,
    const unsigned short* __restrict__ Vtb, unsigned short* __restrict__ Ytp,
    float* __restrict__ denp) {
  __shared__ unsigned short sm[20480];  // 40960 B static
  const int tid = threadIdx.x;
  const int w = tid >> 6, l = tid & 63;
  const int l15 = l & 15, lh = l >> 4;
  const int b = blockIdx.y, sp = blockIdx.z;
  const int n0 = blockIdx.x * 64;
  const int kvbase = sp * 1024;  // 4 splits x 1024 keys

  // Q B-fragments: row n0+w*16+l15, k = lh*8 + ko*32 + j
  bf16x8 qf[4];
  {
    const unsigned short* qrow = Qb + (size_t)(b * 4096 + n0 + w * 16 + l15) * 128 + lh * 8;
#pragma unroll
    for (int ko = 0; ko < 4; ++ko) qf[ko] = *(const bf16x8*)(qrow + ko * 32);
  }
  unsigned short* kb = sm;                      // [64][128] (slot s holds chunk s^(m&7))
  unsigned short* vb = sm + 8192;               // [128][64] (slot s holds chunk s^(d&7))
  unsigned short* sP = sm + 16384 + w * 1024;   // per-wave [16 q][64 m]

  f32x4 yacc[8];
#pragma unroll
  for (int i = 0; i < 8; ++i) yacc[i] = (f32x4){0.f, 0.f, 0.f, 0.f};
  float den = 0.f;

  const unsigned short* Kbase = Kb + (size_t)(b * 4096 + kvbase) * 128;
  const unsigned short* Vbase = Vtb + (size_t)(b * 128) * 4096 + kvbase;

  const int kmrow_off = l >> 4;  // row within 4-row group
  const int vdrow_off = l >> 3;  // row within 8-row group

  for (int t = 0; t < 16; ++t) {
    const int koff = t * 64;
    __syncthreads();  // all waves done reading kb/vb from prev tile
#pragma unroll
    for (int it = 0; it < 4; ++it) {
      int mrow = w * 16 + it * 4 + kmrow_off;
      gl16(Kbase + (size_t)(koff + mrow) * 128 + (((l & 15) ^ (mrow & 7)) << 3),
           kb + (w * 16 + it * 4) * 128);
      int drow = w * 32 + it * 8 + vdrow_off;
      gl16(Vbase + (size_t)drow * 4096 + koff + (((l & 7) ^ (drow & 7)) << 3),
           vb + (w * 32 + it * 8) * 64);
    }
    __syncthreads();  // drains vmcnt(0): LDS tiles ready

    // QK^T: S^T[m][q]
    f32x4 sacc[4];
#pragma unroll
    for (int mt = 0; mt < 4; ++mt) sacc[mt] = (f32x4){0.f, 0.f, 0.f, 0.f};
#pragma unroll
    for (int ko = 0; ko < 4; ++ko) {
#pragma unroll
      for (int mt = 0; mt < 4; ++mt) {
        int m = mt * 16 + l15;
        bf16x8 ak = *(const bf16x8*)(kb + m * 128 + (((lh + 4 * ko) ^ (m & 7)) << 3));
        sacc[mt] = __builtin_amdgcn_mfma_f32_16x16x32_bf16(ak, qf[ko], sacc[mt], 0, 0, 0);
      }
    }
    // exp (logits bounded: no max-sub), pack bf16 -> sP[q][m]
    float rs = 0.f;
#pragma unroll
    for (int mt = 0; mt < 4; ++mt) {
      float e0 = __expf(sacc[mt][0]);
      float e1 = __expf(sacc[mt][1]);
      float e2 = __expf(sacc[mt][2]);
      float e3 = __expf(sacc[mt][3]);
      rs += (e0 + e1) + (e2 + e3);
      ushort4 us;
      us.x = f2bf(e0); us.y = f2bf(e1); us.z = f2bf(e2); us.w = f2bf(e3);
      int mblk = mt * 2 + (lh >> 1);
      *(ushort4*)(sP + l15 * 64 + ((mblk ^ (l15 & 7)) << 3) + (lh & 1) * 4) = us;
    }
    rs += __shfl_xor(rs, 16);
    rs += __shfl_xor(rs, 32);
    den += rs;
    // sP wave-private: program order + lgkmcnt suffice
    // PV: Y^T += V^T * P^T
#pragma unroll
    for (int ko = 0; ko < 2; ++ko) {
      bf16x8 bp = *(const bf16x8*)(sP + l15 * 64 + (((lh + 4 * ko) ^ (l15 & 7)) << 3));
#pragma unroll
      for (int dt = 0; dt < 8; ++dt) {
        int d = dt * 16 + l15;
        bf16x8 av = *(const bf16x8*)(vb + d * 64 + (((lh + 4 * ko) ^ (d & 7)) << 3));
        yacc[dt] = __builtin_amdgcn_mfma_f32_16x16x32_bf16(av, bp, yacc[dt], 0, 0, 0);
      }
    }
  }
  // epilogue: unnormalized bf16 partial Y[n][p] (row-major n) and f32 den.
  // yacc[dt][r] = Y^T[p = dt*16+lh*4+r][n = n0+w*16+l15]: consecutive r = consecutive p.
  unsigned short* Yt = Ytp + (size_t)(sp * 4 + b) * 524288 +
                       (size_t)(n0 + w * 16 + l15) * 128;
#pragma unroll
  for (int dt = 0; dt < 8; ++dt) {
    ushort4 us;
    us.x = f2bf(yacc[dt][0]); us.y = f2bf(yacc[dt][1]);
    us.z = f2bf(yacc[dt][2]); us.w = f2bf(yacc[dt][3]);
    *(ushort4*)(Yt + dt * 16 + lh * 4) = us;
  }
  if (lh == 0) denp[(size_t)(sp * 4 + b) * 4096 + n0 + w * 16 + l15] = den;
}

// ---------------- 3) zbn v2: z = Wz*y + bz via MFMA, fused BN stats ----------------
// grid (64 n, 4 b, 4 cq); 256 thr = 4 waves. Block: 64 c x 64 n tile.
// Stage sY[64 n][128 p] (combine 4 bf16 partials, normalize, bf16) and
// sW[64 c][128 p] (Wz -> bf16), both 8-bf16-chunk XOR-swizzled. 32 KB LDS -> 4/CU.
// Wave w: c rows cq*64 + w*16..+15: A=W-rows -> D-rows, B=Y-rows -> D-cols.
__global__ __launch_bounds__(256, 4) void zbn_kernel(
    const unsigned short* __restrict__ Ytp, const float* __restrict__ denp,
    const float* __restrict__ Wz, const float* __restrict__ bz,
    float* __restrict__ Z, float* __restrict__ S1, float* __restrict__ S2) {
  __shared__ unsigned short sY[64 * 128];
  __shared__ unsigned short sW[64 * 128];
  __shared__ float sDen[64];
  const int tid = threadIdx.x;
  const int w = tid >> 6, l = tid & 63;
  const int l15 = l & 15, lh = l >> 4;
  const int b = blockIdx.y;
  const int n0 = blockIdx.x * 64;
  const int c0 = blockIdx.z * 64;
  if (tid < 64) {
    float s = 0.f;
#pragma unroll
    for (int sp = 0; sp < 4; ++sp) s += denp[sp * 16384 + b * 4096 + n0 + tid];
    sDen[tid] = 1.0f / s;
  }
  __syncthreads();
  // stage sY: sum 4 partials, normalize, pack bf16, swizzled
#pragma unroll
  for (int it = 0; it < 4; ++it) {
    int e = it * 256 + tid;
    int n = e >> 4, pc = e & 15;
    size_t o = (size_t)b * 524288 + (size_t)(n0 + n) * 128 + pc * 8;
    float a0 = 0, a1 = 0, a2 = 0, a3 = 0, a4 = 0, a5 = 0, a6 = 0, a7 = 0;
#pragma unroll
    for (int sp = 0; sp < 4; ++sp) {
      uint4 v = *(const uint4*)(Ytp + (size_t)sp * 2097152 + o);
      a0 += bflo(v.x); a1 += bfhi(v.x);
      a2 += bflo(v.y); a3 += bfhi(v.y);
      a4 += bflo(v.z); a5 += bfhi(v.z);
      a6 += bflo(v.w); a7 += bfhi(v.w);
    }
    float idn = sDen[n];
    ushort8v us;
    us[0] = f2bf(a0 * idn); us[1] = f2bf(a1 * idn);
    us[2] = f2bf(a2 * idn); us[3] = f2bf(a3 * idn);
    us[4] = f2bf(a4 * idn); us[5] = f2bf(a5 * idn);
    us[6] = f2bf(a6 * idn); us[7] = f2bf(a7 * idn);
    *(ushort8v*)(sY + n * 128 + ((pc ^ (n & 7)) << 3)) = us;
  }
  // stage sW: f32 -> bf16, swizzled
#pragma unroll
  for (int it = 0; it < 4; ++it) {
    int e = it * 256 + tid;
    int c = e >> 4, pc = e & 15;
    const float* wsrc = Wz + (size_t)(c0 + c) * 128 + pc * 8;
    float4 wa = *(const float4*)(wsrc);
    float4 wb = *(const float4*)(wsrc + 4);
    ushort8v us;
    us[0] = f2bf(wa.x); us[1] = f2bf(wa.y); us[2] = f2bf(wa.z); us[3] = f2bf(wa.w);
    us[4] = f2bf(wb.x); us[5] = f2bf(wb.y); us[6] = f2bf(wb.z); us[7] = f2bf(wb.w);
    *(ushort8v*)(sW + c * 128 + ((pc ^ (c & 7)) << 3)) = us;
  }
  __syncthreads();
  // MFMA: D[c][n] 64x64 block
  f32x4 acc[4];
#pragma unroll
  for (int nt = 0; nt < 4; ++nt) acc[nt] = (f32x4){0.f, 0.f, 0.f, 0.f};
  const int crow = w * 16 + l15;
#pragma unroll
  for (int ko = 0; ko < 4; ++ko) {
    bf16x8 aw = *(const bf16x8*)(sW + crow * 128 + (((lh + 4 * ko) ^ (crow & 7)) << 3));
#pragma unroll
    for (int nt = 0; nt < 4; ++nt) {
      int nrow = nt * 16 + l15;
      bf16x8 by = *(const bf16x8*)(sY + nrow * 128 + (((lh + 4 * ko) ^ (nrow & 7)) << 3));
      acc[nt] = __builtin_amdgcn_mfma_f32_16x16x32_bf16(aw, by, acc[nt], 0, 0, 0);
    }
  }
  // epilogue: z = acc + bz[c]; write Z[b][c][n]; fused stats over this block's 64 n
  const int cb = c0 + w * 16 + lh * 4;  // D row = lh*4 + r
  float4 bzv = *(const float4*)(bz + cb);
  const float* bzf = (const float*)&bzv;
#pragma unroll
  for (int r = 0; r < 4; ++r) {
    float s1 = 0.f, s2 = 0.f;
#pragma unroll
    for (int nt = 0; nt < 4; ++nt) {
      float z = acc[nt][r] + bzf[r];
      Z[(size_t)(b * 256 + cb + r) * 4096 + n0 + nt * 16 + l15] = z;
      s1 += z;
      s2 += z * z;
    }
#pragma unroll
    for (int m = 1; m < 16; m <<= 1) {
      s1 += __shfl_xor(s1, m);
      s2 += __shfl_xor(s2, m);
    }
    if (l15 == 0) {
      atomicAdd(&S1[cb + r], s1);
      atomicAdd(&S2[cb + r], s2);
    }
  }
}

// ---------------- 4) BN finalize ----------------
__global__ void bnfin_kernel(const float* __restrict__ S1, const float* __restrict__ S2,
                             const float* __restrict__ gamma, const float* __restrict__ beta,
                             float* __restrict__ Scale, float* __restrict__ Shift) {
  int c = threadIdx.x;
  const float inv_cnt = 1.0f / 16384.0f;  // B*N
  float mean = S1[c] * inv_cnt;
  float var = S2[c] * inv_cnt - mean * mean;
  var = fmaxf(var, 0.0f);
  float inv = rsqrtf(var + 1e-5f);
  float sc = gamma[c] * inv;
  Scale[c] = sc;
  Shift[c] = beta[c] - mean * sc;
}

// ---------------- 5) out = z*scale + shift + x ----------------
__global__ __launch_bounds__(256) void out_kernel(
    const float* __restrict__ Z, const float* __restrict__ x,
    const float* __restrict__ Scale, const float* __restrict__ Shift,
    float* __restrict__ out) {
  int i4 = blockIdx.x * 256 + threadIdx.x;
  int flat = i4 << 2;
  int c = (flat >> 12) & 255;
  float4 z = *(const float4*)(Z + flat);
  float4 xv = *(const float4*)(x + flat);
  float sc = Scale[c], sh = Shift[c];
  float4 o;
  o.x = z.x * sc + sh + xv.x;
  o.y = z.y * sc + sh + xv.y;
  o.z = z.z * sc + sh + xv.z;
  o.w = z.w * sc + sh + xv.w;
  *(float4*)(out + flat) = o;
}

extern "C" void kernel_launch(void* const* d_in, const int* in_sizes, int n_in,
                              void* d_out, int out_size, void* d_ws, size_t ws_size,
                              hipStream_t stream) {
  (void)in_sizes; (void)n_in; (void)out_size; (void)ws_size;
  const float* x = (const float*)d_in[0];
  const float* Wt = (const float*)d_in[1];
  const float* bt = (const float*)d_in[2];
  const float* Wp = (const float*)d_in[3];
  const float* bp = (const float*)d_in[4];
  const float* Wg = (const float*)d_in[5];
  const float* bg = (const float*)d_in[6];
  const float* Wz = (const float*)d_in[7];
  const float* bz = (const float*)d_in[8];
  const float* gamma = (const float*)d_in[9];
  const float* beta = (const float*)d_in[10];

  unsigned short* Qb = (unsigned short*)d_ws;        // 2,097,152 bf16 (4 MB)
  unsigned short* Kb = Qb + 2097152;                 // 4 MB
  unsigned short* Vtb = Kb + 2097152;                // 4 MB (transposed)
  unsigned short* Ytp = Vtb + 2097152;               // 4 x 2,097,152 bf16 partials Y[n][p]
  float* denp = (float*)(Ytp + 8388608);             // 4 x 16384 f32
  float* Z = denp + 65536;                           // 4,194,304 f32 (16 MB)
  float* S1 = Z + 4194304;                           // 256
  float* S2 = S1 + 256;                              // 256
  float* Scale = S2 + 256;                           // 256
  float* Shift = Scale + 256;                        // 256

  hipMemsetAsync(S1, 0, 512 * sizeof(float), stream);

  proj_kernel<<<dim3(64, 3, 4), 256, 0, stream>>>(x, Wt, bt, Wp, bp, Wg, bg, Qb, Kb, Vtb);
  attn_kernel<<<dim3(64, 4, 4), 256, 0, stream>>>(Qb, Kb, Vtb, Ytp, denp);
  zbn_kernel<<<dim3(64, 4, 4), 256, 0, stream>>>(Ytp, denp, Wz, bz, Z, S1, S2);
  bnfin_kernel<<<1, 256, 0, stream>>>(S1, S2, gamma, beta, Scale, Shift);
  out_kernel<<<4096, 256, 0, stream>>>(Z, x, Scale, Shift, (float*)d_out);
}

// Round 7
// 96.445 us; speedup vs baseline: 8.2520x; 1.6863x over previous
//
#include <hip/hip_runtime.h>

// NonLocal block: B=4, C=256, P=128, H=W=64, N=4096.
// prep(x -> xT[b][n][c] bf16, W -> Wb[3][128][256] bf16) -> proj2 (MFMA: Q,K [b][n][p],
// V^T [b][p][n]) -> MFMA flash-attn (no-max softmax, kv-split=4, gload_lds staging,
// bf16 partials Y[n][p]) -> zbn (MFMA z=Wz*y, BN partials -> S1p/S2p, NO atomics)
// -> bnfin (256-block reduce) -> elementwise out.
// R7: non-attn tail was ~102 us vs ~37 modeled. Removed zbn's 131k contended atomics
// (partial stores + reduction kernel) and MFMA-ized proj (last fp32 GEMM).

#define SCALE_ 0.08838834764831845f  // 1/sqrt(128)

typedef __bf16 bf16x8 __attribute__((ext_vector_type(8)));
typedef float f32x4 __attribute__((ext_vector_type(4)));
typedef unsigned short ushort8v __attribute__((ext_vector_type(8)));

__device__ inline unsigned short f2bf(float f) {  // RNE float->bf16
  unsigned int u = __float_as_uint(f);
  u += 0x7fffu + ((u >> 16) & 1u);
  return (unsigned short)(u >> 16);
}
__device__ inline float bflo(unsigned int u) { return __uint_as_float(u << 16); }
__device__ inline float bfhi(unsigned int u) { return __uint_as_float(u & 0xffff0000u); }

// async global->LDS, 16B per lane; LDS dest = wave-uniform base + lane*16 (linear).
__device__ inline void gl16(const unsigned short* g, unsigned short* l) {
  __builtin_amdgcn_global_load_lds(
      (const __attribute__((address_space(1))) unsigned int*)(g),
      (__attribute__((address_space(3))) unsigned int*)(l), 16, 0, 0);
}

// ---------------- 0) prep: xT[b][n][c] bf16 + Wb[3][128][256] bf16 ----------------
// grid (80, 4): bx<64 -> transpose tile (b=by, n0=bx*64); bx>=64 && by==0 -> W convert.
__global__ __launch_bounds__(256) void prep_kernel(
    const float* __restrict__ x,
    const float* __restrict__ Wt, const float* __restrict__ Wp, const float* __restrict__ Wg,
    unsigned short* __restrict__ xT, unsigned short* __restrict__ Wb) {
  const int tid = threadIdx.x;
  const int bx = blockIdx.x, b = blockIdx.y;
  if (bx >= 64) {
    if (b != 0) return;
#pragma unroll
    for (int it = 0; it < 3; ++it) {
      int k = (bx - 64) * 256 + tid + it * 4096;  // 0..12287
      const float* src = (k < 4096 ? Wt : (k < 8192 ? Wp : Wg)) + (size_t)(k & 4095) * 8;
      float4 a = *(const float4*)src, c = *(const float4*)(src + 4);
      ushort8v us;
      us[0] = f2bf(a.x); us[1] = f2bf(a.y); us[2] = f2bf(a.z); us[3] = f2bf(a.w);
      us[4] = f2bf(c.x); us[5] = f2bf(c.y); us[6] = f2bf(c.z); us[7] = f2bf(c.w);
      *(ushort8v*)(Wb + (size_t)k * 8) = us;
    }
    return;
  }
  __shared__ float sT[128 * 68];  // padded stride 68 (16B-aligned, conflict-free cols)
  const int w = tid >> 6, l = tid & 63;
  const int n0 = bx * 64;
  for (int half = 0; half < 2; ++half) {
    if (half) __syncthreads();  // prev reads done before overwrite
#pragma unroll
    for (int it = 0; it < 8; ++it) {
      int e = it * 256 + tid;
      int c = e >> 4, n4 = e & 15;
      float4 v = *(const float4*)(x + (size_t)(b * 256 + half * 128 + c) * 4096 + n0 + n4 * 4);
      *(float4*)(sT + c * 68 + n4 * 4) = v;
    }
    __syncthreads();
#pragma unroll
    for (int it = 0; it < 4; ++it) {
      int c8 = it * 4 + w;  // 0..15 within half
      int n = l;
      ushort8v us;
#pragma unroll
      for (int j = 0; j < 8; ++j) us[j] = f2bf(sT[(c8 * 8 + j) * 68 + n]);
      *(ushort8v*)(xT + (size_t)b * 1048576 + (size_t)(n0 + n) * 256 + half * 128 + c8 * 8) = us;
    }
  }
}

// ---------------- 1) proj2: Q,K,Vt via MFMA ----------------
// grid (64 ntile, 4 b, 3 sel); 256 thr = 4 waves. D[p][n] = W[p][c] * xT[n][c]^T.
// LDS: sX[64 n][256 c] (8-chunk slots, low3 XOR n&7) + sW[128 p][64 c] (slots XOR p&7),
// both staged via gl16 with pre-swizzled global source. 48 KB -> 3 blocks/CU.
__global__ __launch_bounds__(256, 3) void proj_kernel(
    const unsigned short* __restrict__ xT, const unsigned short* __restrict__ Wb,
    const float* __restrict__ bt, const float* __restrict__ bp, const float* __restrict__ bg,
    unsigned short* __restrict__ Qb, unsigned short* __restrict__ Kb,
    unsigned short* __restrict__ Vtb) {
  __shared__ unsigned short sX[64 * 256];
  __shared__ unsigned short sW[128 * 64];
  const int tid = threadIdx.x;
  const int w = tid >> 6, l = tid & 63;
  const int l15 = l & 15, lh = l >> 4;
  const int n0 = blockIdx.x * 64;
  const int b = blockIdx.y;
  const int sel = blockIdx.z;
  const unsigned short* xTb = xT + (size_t)b * 1048576;
  const unsigned short* Ws = Wb + (size_t)sel * 32768;
  // stage sX once: rows w*16+it*2+(l>>5), slot l&31; src chunk = (s&24)|((s&7)^(row&7))
#pragma unroll
  for (int it = 0; it < 8; ++it) {
    int row = w * 16 + it * 2 + (l >> 5);
    int s = l & 31;
    int src = (s & 24) | ((s & 7) ^ (row & 7));
    gl16(xTb + (size_t)(n0 + row) * 256 + src * 8, sX + (w * 16 + it * 2) * 256);
  }
  f32x4 acc[2][4];
#pragma unroll
  for (int mt = 0; mt < 2; ++mt)
#pragma unroll
    for (int nt = 0; nt < 4; ++nt) acc[mt][nt] = (f32x4){0.f, 0.f, 0.f, 0.f};

  for (int ko4 = 0; ko4 < 4; ++ko4) {
    __syncthreads();  // prev sW reads done (also drains sX staging on first iter)
#pragma unroll
    for (int it = 0; it < 4; ++it) {
      int p = w * 32 + it * 8 + (l >> 3);
      int s = l & 7;
      gl16(Ws + (size_t)p * 256 + ko4 * 64 + ((s ^ (p & 7)) * 8),
           sW + (w * 32 + it * 8) * 64);
    }
    __syncthreads();  // sW chunk ready
#pragma unroll
    for (int ko2 = 0; ko2 < 2; ++ko2) {
      bf16x8 af[2];
#pragma unroll
      for (int mt = 0; mt < 2; ++mt) {
        int p = w * 32 + mt * 16 + l15;
        af[mt] = *(const bf16x8*)(sW + p * 64 + (((ko2 * 4 + lh) ^ (p & 7)) << 3));
      }
#pragma unroll
      for (int nt = 0; nt < 4; ++nt) {
        int n = nt * 16 + l15;
        int ci = ko4 * 8 + ko2 * 4 + lh;
        int slot = (ci & 24) | ((ci & 7) ^ (n & 7));
        bf16x8 bfv = *(const bf16x8*)(sX + n * 256 + (slot << 3));
#pragma unroll
        for (int mt = 0; mt < 2; ++mt)
          acc[mt][nt] = __builtin_amdgcn_mfma_f32_16x16x32_bf16(af[mt], bfv, acc[mt][nt], 0, 0, 0);
      }
    }
  }
  const float* bias = sel == 0 ? bt : (sel == 1 ? bp : bg);
  const float scl = sel == 0 ? SCALE_ : 1.0f;
#pragma unroll
  for (int mt = 0; mt < 2; ++mt) {
    int pb = w * 32 + mt * 16 + lh * 4;
    float4 bv = *(const float4*)(bias + pb);
    const float* bvf = (const float*)&bv;
    if (sel < 2) {
      unsigned short* dst = (sel == 0 ? Qb : Kb) + (size_t)b * 524288;
#pragma unroll
      for (int nt = 0; nt < 4; ++nt) {
        ushort4 us;
        us.x = f2bf((acc[mt][nt][0] + bv.x) * scl);
        us.y = f2bf((acc[mt][nt][1] + bv.y) * scl);
        us.z = f2bf((acc[mt][nt][2] + bv.z) * scl);
        us.w = f2bf((acc[mt][nt][3] + bv.w) * scl);
        *(ushort4*)(dst + (size_t)(n0 + nt * 16 + l15) * 128 + pb) = us;
      }
    } else {
      unsigned short* dst = Vtb + (size_t)b * 524288;
#pragma unroll
      for (int nt = 0; nt < 4; ++nt)
#pragma unroll
        for (int r = 0; r < 4; ++r)
          dst[(size_t)(pb + r) * 4096 + n0 + nt * 16 + l15] = f2bf(acc[mt][nt][r] + bvf[r]);
    }
  }
}

// ---------------- 2) MFMA flash attention (unchanged from R6) ----------------
__global__ __launch_bounds__(256, 4) void attn_kernel(
    const unsigned short* __restrict__ Qb, const unsigned short* __restrict__ Kb,
    const unsigned short* __restrict__ Vtb, unsigned short* __restrict__ Ytp,
    float* __restrict__ denp) {
  __shared__ unsigned short sm[20480];  // 40960 B static
  const int tid = threadIdx.x;
  const int w = tid >> 6, l = tid & 63;
  const int l15 = l & 15, lh = l >> 4;
  const int b = blockIdx.y, sp = blockIdx.z;
  const int n0 = blockIdx.x * 64;
  const int kvbase = sp * 1024;

  bf16x8 qf[4];
  {
    const unsigned short* qrow = Qb + (size_t)(b * 4096 + n0 + w * 16 + l15) * 128 + lh * 8;
#pragma unroll
    for (int ko = 0; ko < 4; ++ko) qf[ko] = *(const bf16x8*)(qrow + ko * 32);
  }
  unsigned short* kb = sm;
  unsigned short* vb = sm + 8192;
  unsigned short* sP = sm + 16384 + w * 1024;

  f32x4 yacc[8];
#pragma unroll
  for (int i = 0; i < 8; ++i) yacc[i] = (f32x4){0.f, 0.f, 0.f, 0.f};
  float den = 0.f;

  const unsigned short* Kbase = Kb + (size_t)(b * 4096 + kvbase) * 128;
  const unsigned short* Vbase = Vtb + (size_t)(b * 128) * 4096 + kvbase;

  const int kmrow_off = l >> 4;
  const int vdrow_off = l >> 3;

  for (int t = 0; t < 16; ++t) {
    const int koff = t * 64;
    __syncthreads();
#pragma unroll
    for (int it = 0; it < 4; ++it) {
      int mrow = w * 16 + it * 4 + kmrow_off;
      gl16(Kbase + (size_t)(koff + mrow) * 128 + (((l & 15) ^ (mrow & 7)) << 3),
           kb + (w * 16 + it * 4) * 128);
      int drow = w * 32 + it * 8 + vdrow_off;
      gl16(Vbase + (size_t)drow * 4096 + koff + (((l & 7) ^ (drow & 7)) << 3),
           vb + (w * 32 + it * 8) * 64);
    }
    __syncthreads();

    f32x4 sacc[4];
#pragma unroll
    for (int mt = 0; mt < 4; ++mt) sacc[mt] = (f32x4){0.f, 0.f, 0.f, 0.f};
#pragma unroll
    for (int ko = 0; ko < 4; ++ko) {
#pragma unroll
      for (int mt = 0; mt < 4; ++mt) {
        int m = mt * 16 + l15;
        bf16x8 ak = *(const bf16x8*)(kb + m * 128 + (((lh + 4 * ko) ^ (m & 7)) << 3));
        sacc[mt] = __builtin_amdgcn_mfma_f32_16x16x32_bf16(ak, qf[ko], sacc[mt], 0, 0, 0);
      }
    }
    float rs = 0.f;
#pragma unroll
    for (int mt = 0; mt < 4; ++mt) {
      float e0 = __expf(sacc[mt][0]);
      float e1 = __expf(sacc[mt][1]);
      float e2 = __expf(sacc[mt][2]);
      float e3 = __expf(sacc[mt][3]);
      rs += (e0 + e1) + (e2 + e3);
      ushort4 us;
      us.x = f2bf(e0); us.y = f2bf(e1); us.z = f2bf(e2); us.w = f2bf(e3);
      int mblk = mt * 2 + (lh >> 1);
      *(ushort4*)(sP + l15 * 64 + ((mblk ^ (l15 & 7)) << 3) + (lh & 1) * 4) = us;
    }
    rs += __shfl_xor(rs, 16);
    rs += __shfl_xor(rs, 32);
    den += rs;
#pragma unroll
    for (int ko = 0; ko < 2; ++ko) {
      bf16x8 bp = *(const bf16x8*)(sP + l15 * 64 + (((lh + 4 * ko) ^ (l15 & 7)) << 3));
#pragma unroll
      for (int dt = 0; dt < 8; ++dt) {
        int d = dt * 16 + l15;
        bf16x8 av = *(const bf16x8*)(vb + d * 64 + (((lh + 4 * ko) ^ (d & 7)) << 3));
        yacc[dt] = __builtin_amdgcn_mfma_f32_16x16x32_bf16(av, bp, yacc[dt], 0, 0, 0);
      }
    }
  }
  unsigned short* Yt = Ytp + (size_t)(sp * 4 + b) * 524288 +
                       (size_t)(n0 + w * 16 + l15) * 128;
#pragma unroll
  for (int dt = 0; dt < 8; ++dt) {
    ushort4 us;
    us.x = f2bf(yacc[dt][0]); us.y = f2bf(yacc[dt][1]);
    us.z = f2bf(yacc[dt][2]); us.w = f2bf(yacc[dt][3]);
    *(ushort4*)(Yt + dt * 16 + lh * 4) = us;
  }
  if (lh == 0) denp[(size_t)(sp * 4 + b) * 4096 + n0 + w * 16 + l15] = den;
}

// ---------------- 3) zbn: z = Wz*y + bz via MFMA; BN partials (NO atomics) ----------------
__global__ __launch_bounds__(256, 4) void zbn_kernel(
    const unsigned short* __restrict__ Ytp, const float* __restrict__ denp,
    const float* __restrict__ Wz, const float* __restrict__ bz,
    float* __restrict__ Z, float* __restrict__ S1p, float* __restrict__ S2p) {
  __shared__ unsigned short sY[64 * 128];
  __shared__ unsigned short sW[64 * 128];
  __shared__ float sDen[64];
  const int tid = threadIdx.x;
  const int w = tid >> 6, l = tid & 63;
  const int l15 = l & 15, lh = l >> 4;
  const int bx = blockIdx.x;
  const int b = blockIdx.y;
  const int n0 = bx * 64;
  const int c0 = blockIdx.z * 64;
  if (tid < 64) {
    float s = 0.f;
#pragma unroll
    for (int sp = 0; sp < 4; ++sp) s += denp[sp * 16384 + b * 4096 + n0 + tid];
    sDen[tid] = 1.0f / s;
  }
  __syncthreads();
#pragma unroll
  for (int it = 0; it < 4; ++it) {
    int e = it * 256 + tid;
    int n = e >> 4, pc = e & 15;
    size_t o = (size_t)b * 524288 + (size_t)(n0 + n) * 128 + pc * 8;
    float a0 = 0, a1 = 0, a2 = 0, a3 = 0, a4 = 0, a5 = 0, a6 = 0, a7 = 0;
#pragma unroll
    for (int sp = 0; sp < 4; ++sp) {
      uint4 v = *(const uint4*)(Ytp + (size_t)sp * 2097152 + o);
      a0 += bflo(v.x); a1 += bfhi(v.x);
      a2 += bflo(v.y); a3 += bfhi(v.y);
      a4 += bflo(v.z); a5 += bfhi(v.z);
      a6 += bflo(v.w); a7 += bfhi(v.w);
    }
    float idn = sDen[n];
    ushort8v us;
    us[0] = f2bf(a0 * idn); us[1] = f2bf(a1 * idn);
    us[2] = f2bf(a2 * idn); us[3] = f2bf(a3 * idn);
    us[4] = f2bf(a4 * idn); us[5] = f2bf(a5 * idn);
    us[6] = f2bf(a6 * idn); us[7] = f2bf(a7 * idn);
    *(ushort8v*)(sY + n * 128 + ((pc ^ (n & 7)) << 3)) = us;
  }
#pragma unroll
  for (int it = 0; it < 4; ++it) {
    int e = it * 256 + tid;
    int c = e >> 4, pc = e & 15;
    const float* wsrc = Wz + (size_t)(c0 + c) * 128 + pc * 8;
    float4 wa = *(const float4*)(wsrc);
    float4 wb = *(const float4*)(wsrc + 4);
    ushort8v us;
    us[0] = f2bf(wa.x); us[1] = f2bf(wa.y); us[2] = f2bf(wa.z); us[3] = f2bf(wa.w);
    us[4] = f2bf(wb.x); us[5] = f2bf(wb.y); us[6] = f2bf(wb.z); us[7] = f2bf(wb.w);
    *(ushort8v*)(sW + c * 128 + ((pc ^ (c & 7)) << 3)) = us;
  }
  __syncthreads();
  f32x4 acc[4];
#pragma unroll
  for (int nt = 0; nt < 4; ++nt) acc[nt] = (f32x4){0.f, 0.f, 0.f, 0.f};
  const int crow = w * 16 + l15;
#pragma unroll
  for (int ko = 0; ko < 4; ++ko) {
    bf16x8 aw = *(const bf16x8*)(sW + crow * 128 + (((lh + 4 * ko) ^ (crow & 7)) << 3));
#pragma unroll
    for (int nt = 0; nt < 4; ++nt) {
      int nrow = nt * 16 + l15;
      bf16x8 by = *(const bf16x8*)(sY + nrow * 128 + (((lh + 4 * ko) ^ (nrow & 7)) << 3));
      acc[nt] = __builtin_amdgcn_mfma_f32_16x16x32_bf16(aw, by, acc[nt], 0, 0, 0);
    }
  }
  const int cb = c0 + w * 16 + lh * 4;
  float4 bzv = *(const float4*)(bz + cb);
  const float* bzf = (const float*)&bzv;
#pragma unroll
  for (int r = 0; r < 4; ++r) {
    float s1 = 0.f, s2 = 0.f;
#pragma unroll
    for (int nt = 0; nt < 4; ++nt) {
      float z = acc[nt][r] + bzf[r];
      Z[(size_t)(b * 256 + cb + r) * 4096 + n0 + nt * 16 + l15] = z;
      s1 += z;
      s2 += z * z;
    }
#pragma unroll
    for (int m = 1; m < 16; m <<= 1) {
      s1 += __shfl_xor(s1, m);
      s2 += __shfl_xor(s2, m);
    }
    if (l15 == 0) {
      S1p[(size_t)(cb + r) * 256 + b * 64 + bx] = s1;
      S2p[(size_t)(cb + r) * 256 + b * 64 + bx] = s2;
    }
  }
}

// ---------------- 4) BN finalize: reduce 256 partials per channel ----------------
__global__ __launch_bounds__(256) void bnfin_kernel(
    const float* __restrict__ S1p, const float* __restrict__ S2p,
    const float* __restrict__ gamma, const float* __restrict__ beta,
    float* __restrict__ Scale, float* __restrict__ Shift) {
  __shared__ float r1[4], r2[4];
  const int c = blockIdx.x, tid = threadIdx.x;
  float s1 = S1p[(size_t)c * 256 + tid];
  float s2 = S2p[(size_t)c * 256 + tid];
#pragma unroll
  for (int m = 1; m < 64; m <<= 1) {
    s1 += __shfl_xor(s1, m);
    s2 += __shfl_xor(s2, m);
  }
  if ((tid & 63) == 0) { r1[tid >> 6] = s1; r2[tid >> 6] = s2; }
  __syncthreads();
  if (tid == 0) {
    float S1t = (r1[0] + r1[1]) + (r1[2] + r1[3]);
    float S2t = (r2[0] + r2[1]) + (r2[2] + r2[3]);
    const float inv_cnt = 1.0f / 16384.0f;  // B*N
    float mean = S1t * inv_cnt;
    float var = fmaxf(S2t * inv_cnt - mean * mean, 0.0f);
    float inv = rsqrtf(var + 1e-5f);
    float sc = gamma[c] * inv;
    Scale[c] = sc;
    Shift[c] = beta[c] - mean * sc;
  }
}

// ---------------- 5) out = z*scale + shift + x ----------------
__global__ __launch_bounds__(256) void out_kernel(
    const float* __restrict__ Z, const float* __restrict__ x,
    const float* __restrict__ Scale, const float* __restrict__ Shift,
    float* __restrict__ out) {
  int i4 = blockIdx.x * 256 + threadIdx.x;
  int flat = i4 << 2;
  int c = (flat >> 12) & 255;
  float4 z = *(const float4*)(Z + flat);
  float4 xv = *(const float4*)(x + flat);
  float sc = Scale[c], sh = Shift[c];
  float4 o;
  o.x = z.x * sc + sh + xv.x;
  o.y = z.y * sc + sh + xv.y;
  o.z = z.z * sc + sh + xv.z;
  o.w = z.w * sc + sh + xv.w;
  *(float4*)(out + flat) = o;
}

extern "C" void kernel_launch(void* const* d_in, const int* in_sizes, int n_in,
                              void* d_out, int out_size, void* d_ws, size_t ws_size,
                              hipStream_t stream) {
  (void)in_sizes; (void)n_in; (void)out_size; (void)ws_size;
  const float* x = (const float*)d_in[0];
  const float* Wt = (const float*)d_in[1];
  const float* bt = (const float*)d_in[2];
  const float* Wp = (const float*)d_in[3];
  const float* bp = (const float*)d_in[4];
  const float* Wg = (const float*)d_in[5];
  const float* bg = (const float*)d_in[6];
  const float* Wz = (const float*)d_in[7];
  const float* bz = (const float*)d_in[8];
  const float* gamma = (const float*)d_in[9];
  const float* beta = (const float*)d_in[10];

  unsigned short* Qb = (unsigned short*)d_ws;        // 4 MB
  unsigned short* Kb = Qb + 2097152;                 // 4 MB
  unsigned short* Vtb = Kb + 2097152;                // 4 MB
  unsigned short* Ytp = Vtb + 2097152;               // 16 MB (4 bf16 partials Y[n][p])
  float* denp = (float*)(Ytp + 8388608);             // 256 KB
  float* Z = denp + 65536;                           // 16 MB
  float* Scale = Z + 4194304;                        // 1 KB
  float* Shift = Scale + 256;

  // liveness aliases (keep total ws at R6's proven 44.3 MB):
  unsigned short* xT = (unsigned short*)Z;           // dead before zbn writes Z
  unsigned short* Wb = (unsigned short*)denp;        // dead before attn writes denp
  float* S1p = (float*)Qb;                           // used after attn (Qb dead)
  float* S2p = S1p + 65536;

  prep_kernel<<<dim3(80, 4), 256, 0, stream>>>(x, Wt, Wp, Wg, xT, Wb);
  proj_kernel<<<dim3(64, 4, 3), 256, 0, stream>>>(xT, Wb, bt, bp, bg, Qb, Kb, Vtb);
  attn_kernel<<<dim3(64, 4, 4), 256, 0, stream>>>(Qb, Kb, Vtb, Ytp, denp);
  zbn_kernel<<<dim3(64, 4, 4), 256, 0, stream>>>(Ytp, denp, Wz, bz, Z, S1p, S2p);
  bnfin_kernel<<<256, 256, 0, stream>>>(S1p, S2p, gamma, beta, Scale, Shift);
  out_kernel<<<4096, 256, 0, stream>>>(Z, x, Scale, Shift, (float*)d_out);
}